// Round 2
// baseline (6222.716 us; speedup 1.0000x reference)
//
#include <hip/hip_runtime.h>
#include <math.h>

typedef unsigned short u16;
typedef unsigned long long u64;
typedef __attribute__((ext_vector_type(8))) short bf16x8;   // MFMA A/B frag
typedef __attribute__((ext_vector_type(4))) float f32x4;    // MFMA C/D frag

#define T_STEPS 32
#define BSZ     32
#define N_IN    64
#define H       256
#define N_OUT   64
#define ESTRIDE 9984              // rows = 320*31 + 64 (final fresh block)
#define CLAMP_MIN (-2.0f)
#define CLAMP_MAX ( 2.0f)
#define GNB 32                    // gemm blocks per sample (32-row tiles)

// ---------------------------------------------------------------------------
// Fragment-packed layout "B" (8B-quad granular):
//   element (row R, k):  RT=R>>4, m=R&15, KC=k>>5, qq=(k&31)>>3, h=(k&7)>>2, v=k&3
//   u16 offset = ((RT*8+KC)*4+qq)*128 + m*8 + h*4 + v
// A/B-frag load for (RT,KC), lane(m,q): contiguous 16B at ((RT*8+KC)*4+q)*128*2B.
// C^T store (operand-swapped mfma): lane's 4 acc values = 8B contiguous; wave
// covers 512B contiguous.
// ---------------------------------------------------------------------------

__device__ inline u16 f2bf(float x) {                       // RTNE fp32->bf16
    unsigned u = __builtin_bit_cast(unsigned, x);
    unsigned r = u + 0x7FFFu + ((u >> 16) & 1u);
    return (u16)(r >> 16);
}

__device__ __forceinline__ void gl_lds16(const u16* g, u16* l) {
    __builtin_amdgcn_global_load_lds(
        (const __attribute__((address_space(1))) unsigned int*)g,
        (__attribute__((address_space(3))) unsigned int*)l,
        16, 0, 0);
}

// ---------------------------------------------------------------------------
__global__ void transpose_k(const float* __restrict__ src, float* __restrict__ dst,
                            int R, int C)
{
    __shared__ float tile[32][33];
    int bi = blockIdx.y, bj = blockIdx.x;
    int r0 = threadIdx.x >> 5, c = threadIdx.x & 31;
    #pragma unroll
    for (int rr = 0; rr < 4; ++rr) {
        int r = r0 * 4 + rr;
        tile[r][c] = src[(bi * 32 + r) * C + bj * 32 + c];
    }
    __syncthreads();
    #pragma unroll
    for (int rr = 0; rr < 4; ++rr) {
        int r = r0 * 4 + rr;
        dst[(bj * 32 + r) * R + bi * 32 + c] = tile[c][r];
    }
}

// ---------------------------------------------------------------------------
// packWih: Wih pairs in layout-B p-order (float2), once. grid 32 x 256.
// ---------------------------------------------------------------------------
__global__ void packWih_k(const float* __restrict__ Wih, float* __restrict__ WihP)
{
    int p = blockIdx.x * 256 + threadIdx.x;   // p < 8192
    int vb = (p & 1) * 2, hh = (p >> 1) & 1, m = (p >> 2) & 15, qq = (p >> 6) & 3;
    int KC = (p >> 8) & 7, RT = p >> 11;
    int i = RT * 16 + m, k = KC * 32 + qq * 8 + hh * 4 + vb;
    ((float2*)WihP)[p] = make_float2(Wih[i * H + k], Wih[i * H + k + 1]);
}

// ---------------------------------------------------------------------------
// prefresh: fresh rows (rho_t * Wih) for ALL t + fresh-rad (plain store —
// first writer of radT[t]). No atomics: rad is a |W| matvec per column.
// grid (T_STEPS, Bc).
// ---------------------------------------------------------------------------
__global__ __launch_bounds__(256) void prefresh_k(
    const float* __restrict__ X, const float* __restrict__ eps,
    const float* __restrict__ Wih, const float* __restrict__ WihP,
    u16* __restrict__ err, float* __restrict__ radT)
{
    __shared__ float rho_s[N_IN];
    const int t = blockIdx.x, bi = blockIdx.y, tid = threadIdx.x;
    if (tid < N_IN) {
        float x = X[((size_t)t * BSZ + bi) * N_IN + tid], e = eps[bi];
        float lo = fmaxf(x - e, CLAMP_MIN), up = fminf(x + e, CLAMP_MAX);
        rho_s[tid] = 0.5f * (up - lo);
    }
    __syncthreads();

    // fresh-rad: column GEMV, coalesced cached loads, no atomics
    float s = 0.f;
    #pragma unroll 8
    for (int i = 0; i < N_IN; ++i)
        s += fabsf(rho_s[i]) * fabsf(Wih[(size_t)i * H + tid]);
    radT[(size_t)t * BSZ * H + (size_t)bi * H + tid] = s;   // baseline (no init_k)

    // err fresh block: coalesced float2 loads from pre-packed WihP
    u16* dst = err + (size_t)bi * ESTRIDE * H + (size_t)(20 * t) * 4096; // row 320t
    const float2* wp = (const float2*)WihP;
    #pragma unroll 4
    for (int iter = 0; iter < 32; ++iter) {
        int p = iter * 256 + tid;
        int i = (p >> 11) * 16 + ((p >> 2) & 15);
        float2 w = wp[p];
        float rho = rho_s[i];
        *(unsigned*)&dst[2 * p] =
            (unsigned)f2bf(rho * w.x) | ((unsigned)f2bf(rho * w.y) << 16);
    }
}

// ---------------------------------------------------------------------------
// prep0: head preactivation at t=0 only.
// ---------------------------------------------------------------------------
__global__ __launch_bounds__(256) void prep0_k(
    const float* __restrict__ X0, const float* __restrict__ eps,
    const float* __restrict__ Wih, const float* __restrict__ bih,
    const float* __restrict__ bhh, float* __restrict__ hp0)
{
    __shared__ float hx[N_IN];
    const int b = blockIdx.x, tid = threadIdx.x;
    if (tid < N_IN) {
        float x = X0[b * N_IN + tid], e = eps[b];
        float l = fmaxf(x - e, CLAMP_MIN), u = fminf(x + e, CLAMP_MAX);
        hx[tid] = 0.5f * (l + u);
    }
    __syncthreads();
    float acc = bih[tid] + bhh[tid];
    #pragma unroll 8
    for (int i = 0; i < N_IN; ++i) acc += hx[i] * Wih[i * H + tid];
    hp0[b * H + tid] = acc;
}

// ---------------------------------------------------------------------------
// step_k: ONE launch per timestep. grid (GNB+9, Bc).
//   bx <  GNB : gemm role — err[0..ntiles*32 rows) <- err @ (lam.Whh), 32-row
//               tiles, sbuf 2x16KB double-buffer via global_load_lds, B-slab
//               packed in-regs from WhhT32*lam (no WTp), operand-swapped MFMA
//               -> C^T direct coalesced global stores, counted vmcnt(8).
//   bx == GNB : head role — hp_new GEMV.
//   bx >  GNB : diag roles (8) — diag rows write + diag-rad column GEMV slice.
// ---------------------------------------------------------------------------
__global__ __launch_bounds__(256, 3) void step_k(
    const float* __restrict__ Xt, const float* __restrict__ eps,
    const float* __restrict__ Wih, const float* __restrict__ Whh,
    const float* __restrict__ WhhT32,
    const float* __restrict__ bih, const float* __restrict__ bhh,
    const float* __restrict__ hp_prev, const float* __restrict__ rad_prev,
    float* __restrict__ hp_new, float* __restrict__ rad_new,
    u16* __restrict__ err, int E_old)
{
    __shared__ u16 sbuf[2][8192];            // 2 x 16KB tile buffers
    __shared__ float smf[H];                 // lam / de / head-vals per role
    const int bx = blockIdx.x, b = blockIdx.y, tid = threadIdx.x;

    if (bx < GNB) {
        const int ntiles = (E_old - H) >> 5;             // 32-row tiles = 10t-8
        if (bx >= ntiles) return;
        u16* errB = err + (size_t)b * ESTRIDE * H;
        const int wave = tid >> 6, lane = tid & 63;
        const int m = lane & 15, q = lane >> 4;

        { // stage first tile early (flies under tanh + B-pack)
            const u16* g = errB + (size_t)bx * 8192;
            #pragma unroll
            for (int r = 0; r < 4; ++r)
                gl_lds16(g + r * 2048 + tid * 8, &sbuf[0][r * 2048 + wave * 512]);
        }
        { // lam -> smf
            float hd = hp_prev[b * H + tid], rv = rad_prev[b * H + tid];
            float lo = hd - rv, up = hd + rv;
            float tl = tanhf(lo), tu = tanhf(up);
            smf[tid] = fminf(1.f - tl * tl, 1.f - tu * tu);
        }
        asm volatile("s_waitcnt lgkmcnt(0)" ::: "memory");
        __builtin_amdgcn_s_barrier();        // lam_s visible (loads still flying)

        // B-slab in regs: wave owns n-cols [wave*64,+64); lam folded on the fly
        bf16x8 bf[4][8];
        #pragma unroll
        for (int nt = 0; nt < 4; ++nt) {
            const int n = wave * 64 + nt * 16 + m;
            #pragma unroll
            for (int kc = 0; kc < 8; ++kc) {
                const int k0 = kc * 32 + q * 8;
                float4 wa = *(const float4*)&WhhT32[(size_t)n * H + k0];
                float4 wb = *(const float4*)&WhhT32[(size_t)n * H + k0 + 4];
                float4 la = *(const float4*)&smf[k0];
                float4 lb = *(const float4*)&smf[k0 + 4];
                bf16x8 f;
                f[0] = (short)f2bf(la.x * wa.x);
                f[1] = (short)f2bf(la.y * wa.y);
                f[2] = (short)f2bf(la.z * wa.z);
                f[3] = (short)f2bf(la.w * wa.w);
                f[4] = (short)f2bf(lb.x * wb.x);
                f[5] = (short)f2bf(lb.y * wb.y);
                f[6] = (short)f2bf(lb.z * wb.z);
                f[7] = (short)f2bf(lb.w * wb.w);
                bf[nt][kc] = f;
            }
        }

        float racc[16];
        #pragma unroll
        for (int i = 0; i < 16; ++i) racc[i] = 0.f;

        asm volatile("s_waitcnt vmcnt(0)" ::: "memory");
        __builtin_amdgcn_s_barrier();        // first tile staged by all waves

        int cur = 0;
        for (int tile = bx; tile < ntiles; tile += GNB) {
            int nxt = tile + GNB;
            if (nxt < ntiles) {              // prefetch next tile
                const u16* g = errB + (size_t)nxt * 8192;
                #pragma unroll
                for (int r = 0; r < 4; ++r)
                    gl_lds16(g + r * 2048 + tid * 8,
                             &sbuf[cur ^ 1][r * 2048 + wave * 512]);
            }

            f32x4 acc[2][4];
            #pragma unroll
            for (int i = 0; i < 2; ++i)
                #pragma unroll
                for (int c = 0; c < 4; ++c) acc[i][c] = (f32x4){0.f, 0.f, 0.f, 0.f};

            #pragma unroll
            for (int kc = 0; kc < 8; ++kc) {
                bf16x8 af[2];
                #pragma unroll
                for (int rt = 0; rt < 2; ++rt)
                    af[rt] = *(const bf16x8*)
                        &sbuf[cur][(((rt * 8 + kc) * 4 + q) << 7) + m * 8];
                #pragma unroll
                for (int nt = 0; nt < 4; ++nt)
                    #pragma unroll
                    for (int rt = 0; rt < 2; ++rt)   // swapped: A=WT, B=err -> C^T
                        acc[rt][nt] = __builtin_amdgcn_mfma_f32_16x16x32_bf16(
                            bf[nt][kc], af[rt], acc[rt][nt], 0, 0, 0);
            }

            // C^T store: lane holds err-row r = rt*16+m, n = NT*16+q*4+v
            #pragma unroll
            for (int rt = 0; rt < 2; ++rt) {
                const size_t rowbase = (size_t)(tile * 2 + rt) * 4096;
                #pragma unroll
                for (int nt = 0; nt < 4; ++nt) {
                    f32x4 v = acc[rt][nt];
                    racc[nt * 4 + 0] += fabsf(v[0]);
                    racc[nt * 4 + 1] += fabsf(v[1]);
                    racc[nt * 4 + 2] += fabsf(v[2]);
                    racc[nt * 4 + 3] += fabsf(v[3]);
                    unsigned lo = (unsigned)f2bf(v[0]) | ((unsigned)f2bf(v[1]) << 16);
                    unsigned hi = (unsigned)f2bf(v[2]) | ((unsigned)f2bf(v[3]) << 16);
                    const int NT  = wave * 4 + nt;
                    const int kcs = NT >> 1;
                    const int qq  = (NT & 1) * 2 + (q >> 1);
                    const size_t off16 = rowbase
                        + (size_t)(((kcs * 4 + qq) << 7) + m * 8 + (q & 1) * 4);
                    *(u64*)&errB[off16] = ((u64)hi << 32) | lo;
                }
            }
            // drain the 4 staging loads (oldest); leave the 8 C-stores in flight
            asm volatile("s_waitcnt vmcnt(8)" ::: "memory");
            __builtin_amdgcn_s_barrier();
            cur ^= 1;
        }

        // rad: reduce over 16 m-lanes, one atomic per n from m==0 lanes
        #pragma unroll
        for (int i = 0; i < 16; ++i) {
            float v = racc[i];
            v += __shfl_xor(v, 1);
            v += __shfl_xor(v, 2);
            v += __shfl_xor(v, 4);
            v += __shfl_xor(v, 8);
            if (m == 0) {
                int nt = i >> 2, vv = i & 3;
                atomicAdd(&rad_new[b * H + wave * 64 + nt * 16 + q * 4 + vv], v);
            }
        }
        return;
    }

    // ---- aux roles: shared tanh transform ----
    float hd = hp_prev[b * H + tid], rv = rad_prev[b * H + tid];
    float lo = hd - rv, up = hd + rv;
    float tl = tanhf(lo), tu = tanhf(up);
    float la = fminf(1.f - tl * tl, 1.f - tu * tu);
    float mu = 0.5f * (tu + tl - la * (up + lo));
    float dd = 0.5f * (tu - tl - la * (up - lo));

    if (bx == GNB) {                         // head role: hp_new GEMV
        float* hv  = smf;
        float* hxr = (float*)sbuf;
        hv[tid] = la * hd + mu;
        if (tid < N_IN) {
            float x = Xt[b * N_IN + tid], e = eps[b];
            float l2 = fmaxf(x - e, CLAMP_MIN), u2 = fminf(x + e, CLAMP_MAX);
            hxr[tid] = 0.5f * (l2 + u2);
        }
        __syncthreads();
        float acc = bih[tid] + bhh[tid];
        #pragma unroll 8
        for (int i = 0; i < N_IN; ++i) acc += hxr[i] * Wih[i * H + tid];
        #pragma unroll 8
        for (int j = 0; j < H; ++j) acc += hv[j] * Whh[j * H + tid];
        hp_new[b * H + tid] = acc;
        return;
    }

    // diag roles: rrole in [0,8), rows [rrole*32, rrole*32+32) of diag block
    const int rrole = bx - GNB - 1;
    float* de_s = smf;
    de_s[tid] = dd;
    __syncthreads();
    u16* errB = err + (size_t)b * ESTRIDE * H;
    const int diagRTbase = (E_old - H) >> 4;
    #pragma unroll 4
    for (int iter = 0; iter < 16; ++iter) {
        int p = (rrole * 16 + iter) * 256 + tid;
        int vb = (p & 1) * 2, hh = (p >> 1) & 1, mm = (p >> 2) & 15, qq = (p >> 6) & 3;
        int KC = (p >> 8) & 7, RT = p >> 11;
        int i = RT * 16 + mm, k = KC * 32 + qq * 8 + hh * 4 + vb;
        float dv = de_s[i];
        float v0 = dv * Whh[(size_t)i * H + k];
        float v1 = dv * Whh[(size_t)i * H + k + 1];
        *(unsigned*)&errB[(size_t)diagRTbase * 4096 + 2 * p] =
            (unsigned)f2bf(v0) | ((unsigned)f2bf(v1) << 16);
    }
    // diag-rad slice: column GEMV over this role's 32 rows, no LDS atomics
    float s = 0.f;
    #pragma unroll 8
    for (int ii = 0; ii < 32; ++ii) {
        int i = rrole * 32 + ii;
        s += fabsf(de_s[i]) * fabsf(Whh[(size_t)i * H + tid]);
    }
    atomicAdd(&rad_new[b * H + tid], s);
}

// ---------------------------------------------------------------------------
__global__ __launch_bounds__(256) void tanh_final_k(
    const float* __restrict__ hp, const float* __restrict__ rad,
    float* __restrict__ lam, float* __restrict__ de, float* __restrict__ head_h)
{
    const int b = blockIdx.x, h = threadIdx.x;
    float hd = hp[b * H + h], r = rad[b * H + h];
    float l = hd - r, u = hd + r;
    float tl = tanhf(l), tu = tanhf(u);
    float la = fminf(1.f - tl * tl, 1.f - tu * tu);
    float mu = 0.5f * (tu + tl - la * (u + l));
    float dd = 0.5f * (tu - tl - la * (u - l));
    lam[b * H + h] = la;
    de[b * H + h]  = dd;
    head_h[b * H + h] = la * hd + mu;
}

// ---------------------------------------------------------------------------
// pack WoT frag-packed (layout B), lam folded. grid Bc x 256.
// ---------------------------------------------------------------------------
__global__ __launch_bounds__(256) void packWoT_k(
    const float* __restrict__ WoT32, const float* __restrict__ lam,
    u16* __restrict__ WoTp)
{
    const int b = blockIdx.x, tid = threadIdx.x;
    __shared__ float lam_s[H];
    lam_s[tid] = lam[b * H + tid];
    __syncthreads();
    u16* dst = WoTp + (size_t)b * N_OUT * H;
    #pragma unroll 4
    for (int iter = 0; iter < 32; ++iter) {
        int p = iter * 256 + tid;
        int vb = (p & 1) * 2, hh = (p >> 1) & 1, m = (p >> 2) & 15, qq = (p >> 6) & 3;
        int KC = (p >> 8) & 7, RT = p >> 11;   // RT < 4
        int n = RT * 16 + m, k = KC * 32 + qq * 8 + hh * 4 + vb;
        *(unsigned*)&dst[2 * p] =
              (unsigned)f2bf(lam_s[k]     * WoT32[(size_t)n * H + k])
            | ((unsigned)f2bf(lam_s[k + 1] * WoT32[(size_t)n * H + k + 1]) << 16);
    }
}

// ---------------------------------------------------------------------------
__global__ void head_out_k(
    const float* __restrict__ head_h, const float* __restrict__ de,
    const float* __restrict__ Wo, const float* __restrict__ bo,
    float* __restrict__ head_out, float* __restrict__ rad_out)
{
    const int b = blockIdx.x, o = threadIdx.x;
    float acc = bo[o], accR = 0.f;
    #pragma unroll 4
    for (int j = 0; j < H; ++j) {
        float w = Wo[j * N_OUT + o];
        acc  += head_h[b * H + j] * w;
        accR += fabsf(de[b * H + j] * w);
    }
    head_out[b * N_OUT + o] = acc;
    rad_out[b * N_OUT + o]  = accR;
}

// ---------------------------------------------------------------------------
// final radius: rad_out += sum_rows |err @ WoTp^T| over all ESTRIDE rows.
// ---------------------------------------------------------------------------
__global__ __launch_bounds__(256) void gemm_out_k(
    const u16* __restrict__ err, const u16* __restrict__ WoTp,
    float* __restrict__ rad_out)
{
    __shared__ float rad_s[N_OUT];
    const int b = blockIdx.y, row0 = blockIdx.x * 256, tid = threadIdx.x;
    const int wave = tid >> 6, lane = tid & 63;
    const int m = lane & 15, q = lane >> 4;
    const u16* errB = err + (size_t)b * ESTRIDE * H;
    const u16* Wb   = WoTp + (size_t)b * N_OUT * H;

    if (tid < N_OUT) rad_s[tid] = 0.f;
    __syncthreads();

    f32x4 acc[4][4];
    #pragma unroll
    for (int i = 0; i < 4; ++i)
        #pragma unroll
        for (int c = 0; c < 4; ++c) acc[i][c] = (f32x4){0.f, 0.f, 0.f, 0.f};

    const int tile0 = (row0 >> 4) + wave * 4;
    #pragma unroll
    for (int kc = 0; kc < 8; ++kc) {
        bf16x8 af[4], bw[4];
        #pragma unroll
        for (int rt = 0; rt < 4; ++rt)
            af[rt] = *(const bf16x8*)
                &errB[(size_t)(((((tile0 + rt) * 8 + kc) * 4 + q) << 7) + m * 8)];
        #pragma unroll
        for (int nt = 0; nt < 4; ++nt)
            bw[nt] = *(const bf16x8*)
                &Wb[(size_t)((((nt * 8 + kc) * 4 + q) << 7) + m * 8)];
        #pragma unroll
        for (int nt = 0; nt < 4; ++nt)
            #pragma unroll
            for (int rt = 0; rt < 4; ++rt)
                acc[rt][nt] = __builtin_amdgcn_mfma_f32_16x16x32_bf16(
                    af[rt], bw[nt], acc[rt][nt], 0, 0, 0);
    }
    #pragma unroll
    for (int nt = 0; nt < 4; ++nt) {
        float s = 0.f;
        #pragma unroll
        for (int rt = 0; rt < 4; ++rt)
            #pragma unroll
            for (int r = 0; r < 4; ++r) s += fabsf(acc[rt][nt][r]);
        atomicAdd(&rad_s[nt * 16 + m], s);
    }
    __syncthreads();
    if (tid < N_OUT) atomicAdd(&rad_out[b * N_OUT + tid], rad_s[tid]);
}

// ---------------------------------------------------------------------------
__global__ void combine_k(const float* __restrict__ head_out,
                          const float* __restrict__ rad_out,
                          float* __restrict__ out)
{
    int i = blockIdx.x * 256 + threadIdx.x;
    if (i < BSZ * N_OUT) {
        float h = head_out[i], r = rad_out[i];
        out[i]               = h - r;
        out[BSZ * N_OUT + i] = h + r;
    }
}

// ---------------------------------------------------------------------------
extern "C" void kernel_launch(void* const* d_in, const int* in_sizes, int n_in,
                              void* d_out, int out_size, void* d_ws, size_t ws_size,
                              hipStream_t stream)
{
    const float* X    = (const float*)d_in[0];
    const float* eps  = (const float*)d_in[1];
    const float* Wih  = (const float*)d_in[2];
    const float* Whh  = (const float*)d_in[3];
    const float* bih  = (const float*)d_in[4];
    const float* bhh  = (const float*)d_in[5];
    const float* Wo   = (const float*)d_in[6];
    const float* bo   = (const float*)d_in[7];
    float* out = (float*)d_out;

    const size_t per_sample = (size_t)ESTRIDE * H * 2 + (size_t)N_OUT * H * 2;
    const size_t shared_b = (size_t)H * H * 4 + (size_t)N_OUT * H * 4
                          + (size_t)N_IN * H * 4                         // WihP
                          + (size_t)2 * BSZ * H * 4                      // hp[2]
                          + (size_t)T_STEPS * BSZ * H * 4                // radT
                          + (size_t)3 * BSZ * H * 4                      // lam/de/head_h
                          + (size_t)2 * BSZ * N_OUT * 4 + 256;
    int Bc = BSZ;
    while (Bc > 1 && (size_t)Bc * per_sample + shared_b > ws_size) Bc >>= 1;

    char* p = (char*)d_ws;
    u16* errP      = (u16*)p;   p += (size_t)Bc * ESTRIDE * H * 2;
    u16* WoTp      = (u16*)p;   p += (size_t)Bc * N_OUT * H * 2;
    float* WhhT32  = (float*)p; p += (size_t)H * H * 4;
    float* WoT32   = (float*)p; p += (size_t)N_OUT * H * 4;
    float* WihP    = (float*)p; p += (size_t)N_IN * H * 4;
    float* hp      = (float*)p; p += (size_t)2 * BSZ * H * 4;
    float* radT    = (float*)p; p += (size_t)T_STEPS * BSZ * H * 4;
    float* lam     = (float*)p; p += (size_t)BSZ * H * 4;
    float* de      = (float*)p; p += (size_t)BSZ * H * 4;
    float* head_h  = (float*)p; p += (size_t)BSZ * H * 4;
    float* head_out= (float*)p; p += (size_t)BSZ * N_OUT * 4;
    float* rad_out = (float*)p;

    transpose_k<<<dim3(H / 32, H / 32), 256, 0, stream>>>(Whh, WhhT32, H, H);
    transpose_k<<<dim3(N_OUT / 32, H / 32), 256, 0, stream>>>(Wo, WoT32, H, N_OUT);
    packWih_k<<<32, 256, 0, stream>>>(Wih, WihP);

    for (int b0 = 0; b0 < BSZ; b0 += Bc) {
        prefresh_k<<<dim3(T_STEPS, Bc), 256, 0, stream>>>(
            X + (size_t)b0 * N_IN, eps + b0, Wih, WihP, errP,
            radT + (size_t)b0 * H);
        prep0_k<<<Bc, 256, 0, stream>>>(
            X + (size_t)b0 * N_IN, eps + b0, Wih, bih, bhh, hp + (size_t)b0 * H);
        for (int t = 1; t < T_STEPS; ++t) {
            int E_old = t * (N_IN + H);
            const float* hp_prev = hp + (size_t)((t - 1) & 1) * BSZ * H + (size_t)b0 * H;
            float*       hp_new  = hp + (size_t)(t & 1) * BSZ * H + (size_t)b0 * H;
            const float* rad_prev = radT + (size_t)(t - 1) * BSZ * H + (size_t)b0 * H;
            float*       rad_new  = radT + (size_t)t * BSZ * H + (size_t)b0 * H;
            step_k<<<dim3(GNB + 9, Bc), 256, 0, stream>>>(
                X + (size_t)(t * BSZ + b0) * N_IN, eps + b0, Wih, Whh, WhhT32,
                bih, bhh, hp_prev, rad_prev, hp_new, rad_new, errP, E_old);
        }
        const float* hp_last = hp + (size_t)((T_STEPS - 1) & 1) * BSZ * H + (size_t)b0 * H;
        const float* rad_last = radT + (size_t)(T_STEPS - 1) * BSZ * H + (size_t)b0 * H;
        tanh_final_k<<<Bc, 256, 0, stream>>>(
            hp_last, rad_last, lam + (size_t)b0 * H, de + (size_t)b0 * H,
            head_h + (size_t)b0 * H);
        packWoT_k<<<Bc, 256, 0, stream>>>(WoT32, lam + (size_t)b0 * H, WoTp);
        head_out_k<<<Bc, 64, 0, stream>>>(
            head_h + (size_t)b0 * H, de + (size_t)b0 * H, Wo, bo,
            head_out + (size_t)b0 * N_OUT, rad_out + (size_t)b0 * N_OUT);
        gemm_out_k<<<dim3(ESTRIDE / 256, Bc), 256, 0, stream>>>(
            errP, WoTp, rad_out + (size_t)b0 * N_OUT);
    }

    combine_k<<<(BSZ * N_OUT + 255) / 256, 256, 0, stream>>>(head_out, rad_out, out);
}

// Round 3
// 2086.688 us; speedup vs baseline: 2.9821x; 2.9821x over previous
//
#include <hip/hip_runtime.h>
#include <math.h>

typedef unsigned short u16;
typedef unsigned long long u64;
typedef __attribute__((ext_vector_type(8))) short bf16x8;   // MFMA A/B frag
typedef __attribute__((ext_vector_type(4))) float f32x4;    // MFMA C/D frag

#define T_STEPS 32
#define BSZ     32
#define N_IN    64
#define H       256
#define N_OUT   64
#define ESTRIDE 9984              // rows = 320*31 + 64 (final fresh block)
#define CLAMP_MIN (-2.0f)
#define CLAMP_MAX ( 2.0f)
#define GNB 16                    // gemm blocks per sample (64-row tiles)

// ---------------------------------------------------------------------------
// Fragment-packed layout "B" (8B-quad granular):
//   element (row R, k):  RT=R>>4, m=R&15, KC=k>>5, qq=(k&31)>>3, h=(k&7)>>2, v=k&3
//   u16 offset = ((RT*8+KC)*4+qq)*128 + m*8 + h*4 + v
// A/B-frag load for (RT,KC), lane(m,q): contiguous 16B at (((RT*8+KC)*4+q)<<7)+m*8.
// Frag element j (j=0..7) corresponds to k = KC*32 + q*8 + j.
// C^T store (operand-swapped mfma): lane's 4 acc values = 8B contiguous.
// ---------------------------------------------------------------------------

__device__ inline u16 f2bf(float x) {                       // RTNE fp32->bf16
    unsigned u = __builtin_bit_cast(unsigned, x);
    unsigned r = u + 0x7FFFu + ((u >> 16) & 1u);
    return (u16)(r >> 16);
}
__device__ inline float bf2f(short s) {
    return __builtin_bit_cast(float, ((unsigned)(u16)s) << 16);
}

__device__ __forceinline__ void gl_lds16(const u16* g, u16* l) {
    __builtin_amdgcn_global_load_lds(
        (const __attribute__((address_space(1))) unsigned int*)g,
        (__attribute__((address_space(3))) unsigned int*)l,
        16, 0, 0);
}

// ---------------------------------------------------------------------------
__global__ void transpose_k(const float* __restrict__ src, float* __restrict__ dst,
                            int R, int C)
{
    __shared__ float tile[32][33];
    int bi = blockIdx.y, bj = blockIdx.x;
    int r0 = threadIdx.x >> 5, c = threadIdx.x & 31;
    #pragma unroll
    for (int rr = 0; rr < 4; ++rr) {
        int r = r0 * 4 + rr;
        tile[r][c] = src[(bi * 32 + r) * C + bj * 32 + c];
    }
    __syncthreads();
    #pragma unroll
    for (int rr = 0; rr < 4; ++rr) {
        int r = r0 * 4 + rr;
        dst[(bj * 32 + r) * R + bi * 32 + c] = tile[c][r];
    }
}

// ---------------------------------------------------------------------------
// packPairs: W (R x 256 fp32) -> float2 pairs in layout-B p-order.
// grid (R*128)/256 blocks x 256.
// ---------------------------------------------------------------------------
__global__ void packPairs_k(const float* __restrict__ W, float* __restrict__ WP)
{
    int p = blockIdx.x * 256 + threadIdx.x;
    int vb = (p & 1) * 2, hh = (p >> 1) & 1, m = (p >> 2) & 15, qq = (p >> 6) & 3;
    int KC = (p >> 8) & 7, RT = p >> 11;
    int i = RT * 16 + m, k = KC * 32 + qq * 8 + hh * 4 + vb;
    ((float2*)WP)[p] = make_float2(W[(size_t)i * H + k], W[(size_t)i * H + k + 1]);
}

// ---------------------------------------------------------------------------
// packWT: WhhT32 (256x256 fp32) -> bf16 layout-B (static, no lam). grid 128x256.
// ---------------------------------------------------------------------------
__global__ void packWT_k(const float* __restrict__ WT32, u16* __restrict__ WTp)
{
    int p = blockIdx.x * 256 + threadIdx.x;     // p < 32768
    int vb = (p & 1) * 2, hh = (p >> 1) & 1, m = (p >> 2) & 15, qq = (p >> 6) & 3;
    int KC = (p >> 8) & 7, RT = p >> 11;
    int n = RT * 16 + m, k = KC * 32 + qq * 8 + hh * 4 + vb;
    *(unsigned*)&WTp[2 * p] =
          (unsigned)f2bf(WT32[(size_t)n * H + k])
        | ((unsigned)f2bf(WT32[(size_t)n * H + k + 1]) << 16);
}

// ---------------------------------------------------------------------------
// prefresh: fresh rows (rho_t * Wih) for ALL t + fresh-rad baseline (plain
// store — first writer of radT[t]). grid (T_STEPS, Bc).
// ---------------------------------------------------------------------------
__global__ __launch_bounds__(256) void prefresh_k(
    const float* __restrict__ X, const float* __restrict__ eps,
    const float* __restrict__ Wih, const float* __restrict__ WihP,
    u16* __restrict__ err, float* __restrict__ radT)
{
    __shared__ float rho_s[N_IN];
    const int t = blockIdx.x, bi = blockIdx.y, tid = threadIdx.x;
    if (tid < N_IN) {
        float x = X[((size_t)t * BSZ + bi) * N_IN + tid], e = eps[bi];
        float lo = fmaxf(x - e, CLAMP_MIN), up = fminf(x + e, CLAMP_MAX);
        rho_s[tid] = 0.5f * (up - lo);
    }
    __syncthreads();

    // fresh-rad: column GEMV, coalesced cached loads, no atomics
    float s = 0.f;
    #pragma unroll 8
    for (int i = 0; i < N_IN; ++i)
        s += fabsf(rho_s[i]) * fabsf(Wih[(size_t)i * H + tid]);
    radT[(size_t)t * BSZ * H + (size_t)bi * H + tid] = s;

    u16* dst = err + (size_t)bi * ESTRIDE * H + (size_t)(20 * t) * 4096; // row 320t
    const float2* wp = (const float2*)WihP;
    #pragma unroll 4
    for (int iter = 0; iter < 32; ++iter) {
        int p = iter * 256 + tid;
        int i = (p >> 11) * 16 + ((p >> 2) & 15);
        float2 w = wp[p];
        float rho = rho_s[i];
        *(unsigned*)&dst[2 * p] =
            (unsigned)f2bf(rho * w.x) | ((unsigned)f2bf(rho * w.y) << 16);
    }
}

// ---------------------------------------------------------------------------
// prep0: head preactivation at t=0 only.
// ---------------------------------------------------------------------------
__global__ __launch_bounds__(256) void prep0_k(
    const float* __restrict__ X0, const float* __restrict__ eps,
    const float* __restrict__ Wih, const float* __restrict__ bih,
    const float* __restrict__ bhh, float* __restrict__ hp0)
{
    __shared__ float hx[N_IN];
    const int b = blockIdx.x, tid = threadIdx.x;
    if (tid < N_IN) {
        float x = X0[b * N_IN + tid], e = eps[b];
        float l = fmaxf(x - e, CLAMP_MIN), u = fminf(x + e, CLAMP_MAX);
        hx[tid] = 0.5f * (l + u);
    }
    __syncthreads();
    float acc = bih[tid] + bhh[tid];
    #pragma unroll 8
    for (int i = 0; i < N_IN; ++i) acc += hx[i] * Wih[i * H + tid];
    hp0[b * H + tid] = acc;
}

// ---------------------------------------------------------------------------
// step_k: ONE launch per timestep. grid (GNB+9, Bc).
//   bx <  GNB : gemm role — round-1-proven core (64-row tiles, 2x32KB LDS
//               dbuf via global_load_lds, counted vmcnt(16) barrier, C^T
//               direct coalesced stores). B-slab = STATIC bf16 WhhTp frags
//               scaled in-registers by lam (one-time per block).
//   bx == GNB : head role — hp_new GEMV.
//   bx >  GNB : diag roles (8) — diag rows (coalesced via WhhP float2) +
//               diag-rad column GEMV slice.
// ---------------------------------------------------------------------------
__global__ __launch_bounds__(256, 2) void step_k(
    const float* __restrict__ Xt, const float* __restrict__ eps,
    const float* __restrict__ Wih, const float* __restrict__ Whh,
    const float* __restrict__ WhhP, const u16* __restrict__ WhhTp,
    const float* __restrict__ bih, const float* __restrict__ bhh,
    const float* __restrict__ hp_prev, const float* __restrict__ rad_prev,
    float* __restrict__ hp_new, float* __restrict__ rad_new,
    u16* __restrict__ err, int E_old)
{
    __shared__ u16 sbuf[2][16384];           // 2 x 32KB tile buffers
    __shared__ float smf[H];                 // lam / de / head-vals per role
    const int bx = blockIdx.x, b = blockIdx.y, tid = threadIdx.x;

    if (bx < GNB) {
        const int ntiles = (E_old - H) >> 6;             // 64-row tiles = 5t-4
        if (bx >= ntiles) return;
        u16* errB = err + (size_t)b * ESTRIDE * H;
        const int wave = tid >> 6, lane = tid & 63;
        const int m = lane & 15, q = lane >> 4;

        { // stage first tile early (flies under tanh + B-load/scale)
            const u16* g = errB + (size_t)bx * 16384;
            #pragma unroll
            for (int r = 0; r < 8; ++r)
                gl_lds16(g + r * 2048 + tid * 8, &sbuf[0][r * 2048 + wave * 512]);
        }

        // B-slab: static bf16 WhhTp frags (L2-hot, shared by all blocks/samples)
        bf16x8 bf[4][8];
        #pragma unroll
        for (int nt = 0; nt < 4; ++nt)
            #pragma unroll
            for (int kc = 0; kc < 8; ++kc)
                bf[nt][kc] = *(const bf16x8*)
                    &WhhTp[(size_t)(((((wave * 4 + nt) * 8 + kc) * 4 + q) << 7) + m * 8)];

        { // lam -> smf
            float hd = hp_prev[b * H + tid], rv = rad_prev[b * H + tid];
            float lo = hd - rv, up = hd + rv;
            float tl = tanhf(lo), tu = tanhf(up);
            smf[tid] = fminf(1.f - tl * tl, 1.f - tu * tu);
        }
        __syncthreads();   // lam visible; drains first tile + B loads (vmcnt 0)

        // fold lam into B-frags in-register (one-time per block)
        #pragma unroll
        for (int nt = 0; nt < 4; ++nt)
            #pragma unroll
            for (int kc = 0; kc < 8; ++kc) {
                const int k0 = kc * 32 + q * 8;
                float4 la = *(const float4*)&smf[k0];
                float4 lb = *(const float4*)&smf[k0 + 4];
                bf16x8 w = bf[nt][kc], f;
                f[0] = (short)f2bf(bf2f(w[0]) * la.x);
                f[1] = (short)f2bf(bf2f(w[1]) * la.y);
                f[2] = (short)f2bf(bf2f(w[2]) * la.z);
                f[3] = (short)f2bf(bf2f(w[3]) * la.w);
                f[4] = (short)f2bf(bf2f(w[4]) * lb.x);
                f[5] = (short)f2bf(bf2f(w[5]) * lb.y);
                f[6] = (short)f2bf(bf2f(w[6]) * lb.z);
                f[7] = (short)f2bf(bf2f(w[7]) * lb.w);
                bf[nt][kc] = f;
            }

        float racc[16];
        #pragma unroll
        for (int i = 0; i < 16; ++i) racc[i] = 0.f;

        int cur = 0;
        for (int tile = bx; tile < ntiles; tile += GNB) {
            int nxt = tile + GNB;
            if (nxt < ntiles) {              // prefetch next tile
                const u16* g = errB + (size_t)nxt * 16384;
                #pragma unroll
                for (int r = 0; r < 8; ++r)
                    gl_lds16(g + r * 2048 + tid * 8,
                             &sbuf[cur ^ 1][r * 2048 + wave * 512]);
            }

            f32x4 acc[4][4];
            #pragma unroll
            for (int i = 0; i < 4; ++i)
                #pragma unroll
                for (int c = 0; c < 4; ++c) acc[i][c] = (f32x4){0.f, 0.f, 0.f, 0.f};

            #pragma unroll
            for (int kc = 0; kc < 8; ++kc) {
                bf16x8 af[4];
                #pragma unroll
                for (int rt = 0; rt < 4; ++rt)
                    af[rt] = *(const bf16x8*)
                        &sbuf[cur][(((rt * 8 + kc) * 4 + q) << 7) + m * 8];
                #pragma unroll
                for (int nt = 0; nt < 4; ++nt)
                    #pragma unroll
                    for (int rt = 0; rt < 4; ++rt)   // swapped: A=WT, B=err -> C^T
                        acc[rt][nt] = __builtin_amdgcn_mfma_f32_16x16x32_bf16(
                            bf[nt][kc], af[rt], acc[rt][nt], 0, 0, 0);
            }

            // C^T store: lane holds err-row r = rt*16+m, n = NT*16+q*4+v
            #pragma unroll
            for (int rt = 0; rt < 4; ++rt) {
                const size_t rowbase = (size_t)(tile * 4 + rt) * 4096;
                #pragma unroll
                for (int nt = 0; nt < 4; ++nt) {
                    f32x4 v = acc[rt][nt];
                    racc[nt * 4 + 0] += fabsf(v[0]);
                    racc[nt * 4 + 1] += fabsf(v[1]);
                    racc[nt * 4 + 2] += fabsf(v[2]);
                    racc[nt * 4 + 3] += fabsf(v[3]);
                    unsigned lo = (unsigned)f2bf(v[0]) | ((unsigned)f2bf(v[1]) << 16);
                    unsigned hi = (unsigned)f2bf(v[2]) | ((unsigned)f2bf(v[3]) << 16);
                    const int NT  = wave * 4 + nt;
                    const int kcs = NT >> 1;
                    const int qq  = (NT & 1) * 2 + (q >> 1);
                    const size_t off16 = rowbase
                        + (size_t)(((kcs * 4 + qq) << 7) + m * 8 + (q & 1) * 4);
                    *(u64*)&errB[off16] = ((u64)hi << 32) | lo;
                }
            }
            // drain prev stores + this tile's 8 staging loads (older);
            // leave the 16 newest C-stores in flight across the barrier.
            asm volatile("s_waitcnt vmcnt(16)" ::: "memory");
            __builtin_amdgcn_s_barrier();
            cur ^= 1;
        }

        // rad: reduce over 16 m-lanes, one atomic per n from m==0 lanes
        #pragma unroll
        for (int i = 0; i < 16; ++i) {
            float v = racc[i];
            v += __shfl_xor(v, 1);
            v += __shfl_xor(v, 2);
            v += __shfl_xor(v, 4);
            v += __shfl_xor(v, 8);
            if (m == 0) {
                int nt = i >> 2, vv = i & 3;
                atomicAdd(&rad_new[b * H + wave * 64 + nt * 16 + q * 4 + vv], v);
            }
        }
        return;
    }

    // ---- aux roles: shared tanh transform ----
    float hd = hp_prev[b * H + tid], rv = rad_prev[b * H + tid];
    float lo = hd - rv, up = hd + rv;
    float tl = tanhf(lo), tu = tanhf(up);
    float la = fminf(1.f - tl * tl, 1.f - tu * tu);
    float mu = 0.5f * (tu + tl - la * (up + lo));
    float dd = 0.5f * (tu - tl - la * (up - lo));

    if (bx == GNB) {                         // head role: hp_new GEMV
        float* hv  = smf;
        float* hxr = (float*)sbuf;
        hv[tid] = la * hd + mu;
        if (tid < N_IN) {
            float x = Xt[b * N_IN + tid], e = eps[b];
            float l2 = fmaxf(x - e, CLAMP_MIN), u2 = fminf(x + e, CLAMP_MAX);
            hxr[tid] = 0.5f * (l2 + u2);
        }
        __syncthreads();
        float acc = bih[tid] + bhh[tid];
        #pragma unroll 8
        for (int i = 0; i < N_IN; ++i) acc += hxr[i] * Wih[i * H + tid];
        #pragma unroll 8
        for (int j = 0; j < H; ++j) acc += hv[j] * Whh[j * H + tid];
        hp_new[b * H + tid] = acc;
        return;
    }

    // diag roles: rrole in [0,8), rows [rrole*32, rrole*32+32) of diag block
    const int rrole = bx - GNB - 1;
    float* de_s = smf;
    de_s[tid] = dd;
    __syncthreads();
    u16* errB = err + (size_t)b * ESTRIDE * H;
    const size_t diagBase = (size_t)((E_old - H) >> 4) * 4096;
    const float2* wp = (const float2*)WhhP;
    #pragma unroll 4
    for (int iter = 0; iter < 16; ++iter) {
        int p = (rrole * 16 + iter) * 256 + tid;
        int i = (p >> 11) * 16 + ((p >> 2) & 15);
        float2 w = wp[p];
        float dv = de_s[i];
        *(unsigned*)&errB[diagBase + 2 * p] =
            (unsigned)f2bf(dv * w.x) | ((unsigned)f2bf(dv * w.y) << 16);
    }
    // diag-rad slice: column GEMV over this role's 32 rows
    float s = 0.f;
    #pragma unroll 8
    for (int ii = 0; ii < 32; ++ii) {
        int i = rrole * 32 + ii;
        s += fabsf(de_s[i]) * fabsf(Whh[(size_t)i * H + tid]);
    }
    atomicAdd(&rad_new[b * H + tid], s);
}

// ---------------------------------------------------------------------------
__global__ __launch_bounds__(256) void tanh_final_k(
    const float* __restrict__ hp, const float* __restrict__ rad,
    float* __restrict__ lam, float* __restrict__ de, float* __restrict__ head_h)
{
    const int b = blockIdx.x, h = threadIdx.x;
    float hd = hp[b * H + h], r = rad[b * H + h];
    float l = hd - r, u = hd + r;
    float tl = tanhf(l), tu = tanhf(u);
    float la = fminf(1.f - tl * tl, 1.f - tu * tu);
    float mu = 0.5f * (tu + tl - la * (u + l));
    float dd = 0.5f * (tu - tl - la * (u - l));
    lam[b * H + h] = la;
    de[b * H + h]  = dd;
    head_h[b * H + h] = la * hd + mu;
}

// ---------------------------------------------------------------------------
// pack WoT frag-packed (layout B), lam folded. grid Bc x 256.
// ---------------------------------------------------------------------------
__global__ __launch_bounds__(256) void packWoT_k(
    const float* __restrict__ WoT32, const float* __restrict__ lam,
    u16* __restrict__ WoTp)
{
    const int b = blockIdx.x, tid = threadIdx.x;
    __shared__ float lam_s[H];
    lam_s[tid] = lam[b * H + tid];
    __syncthreads();
    u16* dst = WoTp + (size_t)b * N_OUT * H;
    #pragma unroll 4
    for (int iter = 0; iter < 32; ++iter) {
        int p = iter * 256 + tid;
        int vb = (p & 1) * 2, hh = (p >> 1) & 1, m = (p >> 2) & 15, qq = (p >> 6) & 3;
        int KC = (p >> 8) & 7, RT = p >> 11;   // RT < 4
        int n = RT * 16 + m, k = KC * 32 + qq * 8 + hh * 4 + vb;
        *(unsigned*)&dst[2 * p] =
              (unsigned)f2bf(lam_s[k]     * WoT32[(size_t)n * H + k])
            | ((unsigned)f2bf(lam_s[k + 1] * WoT32[(size_t)n * H + k + 1]) << 16);
    }
}

// ---------------------------------------------------------------------------
__global__ void head_out_k(
    const float* __restrict__ head_h, const float* __restrict__ de,
    const float* __restrict__ Wo, const float* __restrict__ bo,
    float* __restrict__ head_out, float* __restrict__ rad_out)
{
    const int b = blockIdx.x, o = threadIdx.x;
    float acc = bo[o], accR = 0.f;
    #pragma unroll 4
    for (int j = 0; j < H; ++j) {
        float w = Wo[j * N_OUT + o];
        acc  += head_h[b * H + j] * w;
        accR += fabsf(de[b * H + j] * w);
    }
    head_out[b * N_OUT + o] = acc;
    rad_out[b * N_OUT + o]  = accR;
}

// ---------------------------------------------------------------------------
// final radius: rad_out += sum_rows |err @ WoTp^T| over all ESTRIDE rows.
// ---------------------------------------------------------------------------
__global__ __launch_bounds__(256) void gemm_out_k(
    const u16* __restrict__ err, const u16* __restrict__ WoTp,
    float* __restrict__ rad_out)
{
    __shared__ float rad_s[N_OUT];
    const int b = blockIdx.y, row0 = blockIdx.x * 256, tid = threadIdx.x;
    const int wave = tid >> 6, lane = tid & 63;
    const int m = lane & 15, q = lane >> 4;
    const u16* errB = err + (size_t)b * ESTRIDE * H;
    const u16* Wb   = WoTp + (size_t)b * N_OUT * H;

    if (tid < N_OUT) rad_s[tid] = 0.f;
    __syncthreads();

    f32x4 acc[4][4];
    #pragma unroll
    for (int i = 0; i < 4; ++i)
        #pragma unroll
        for (int c = 0; c < 4; ++c) acc[i][c] = (f32x4){0.f, 0.f, 0.f, 0.f};

    const int tile0 = (row0 >> 4) + wave * 4;
    #pragma unroll
    for (int kc = 0; kc < 8; ++kc) {
        bf16x8 af[4], bw[4];
        #pragma unroll
        for (int rt = 0; rt < 4; ++rt)
            af[rt] = *(const bf16x8*)
                &errB[(size_t)(((((tile0 + rt) * 8 + kc) * 4 + q) << 7) + m * 8)];
        #pragma unroll
        for (int nt = 0; nt < 4; ++nt)
            bw[nt] = *(const bf16x8*)
                &Wb[(size_t)((((nt * 8 + kc) * 4 + q) << 7) + m * 8)];
        #pragma unroll
        for (int nt = 0; nt < 4; ++nt)
            #pragma unroll
            for (int rt = 0; rt < 4; ++rt)
                acc[rt][nt] = __builtin_amdgcn_mfma_f32_16x16x32_bf16(
                    af[rt], bw[nt], acc[rt][nt], 0, 0, 0);
    }
    #pragma unroll
    for (int nt = 0; nt < 4; ++nt) {
        float s = 0.f;
        #pragma unroll
        for (int rt = 0; rt < 4; ++rt)
            #pragma unroll
            for (int r = 0; r < 4; ++r) s += fabsf(acc[rt][nt][r]);
        atomicAdd(&rad_s[nt * 16 + m], s);
    }
    __syncthreads();
    if (tid < N_OUT) atomicAdd(&rad_out[b * N_OUT + tid], rad_s[tid]);
}

// ---------------------------------------------------------------------------
__global__ void combine_k(const float* __restrict__ head_out,
                          const float* __restrict__ rad_out,
                          float* __restrict__ out)
{
    int i = blockIdx.x * 256 + threadIdx.x;
    if (i < BSZ * N_OUT) {
        float h = head_out[i], r = rad_out[i];
        out[i]               = h - r;
        out[BSZ * N_OUT + i] = h + r;
    }
}

// ---------------------------------------------------------------------------
extern "C" void kernel_launch(void* const* d_in, const int* in_sizes, int n_in,
                              void* d_out, int out_size, void* d_ws, size_t ws_size,
                              hipStream_t stream)
{
    const float* X    = (const float*)d_in[0];
    const float* eps  = (const float*)d_in[1];
    const float* Wih  = (const float*)d_in[2];
    const float* Whh  = (const float*)d_in[3];
    const float* bih  = (const float*)d_in[4];
    const float* bhh  = (const float*)d_in[5];
    const float* Wo   = (const float*)d_in[6];
    const float* bo   = (const float*)d_in[7];
    float* out = (float*)d_out;

    const size_t per_sample = (size_t)ESTRIDE * H * 2 + (size_t)N_OUT * H * 2;
    const size_t shared_b = (size_t)H * H * 4       // WhhT32
                          + (size_t)N_OUT * H * 4   // WoT32
                          + (size_t)N_IN * H * 4    // WihP
                          + (size_t)H * H * 4       // WhhP
                          + (size_t)H * H * 2       // WhhTp
                          + (size_t)2 * BSZ * H * 4                      // hp[2]
                          + (size_t)T_STEPS * BSZ * H * 4                // radT
                          + (size_t)3 * BSZ * H * 4                      // lam/de/head_h
                          + (size_t)2 * BSZ * N_OUT * 4 + 256;
    int Bc = BSZ;
    while (Bc > 1 && (size_t)Bc * per_sample + shared_b > ws_size) Bc >>= 1;

    char* p = (char*)d_ws;
    u16* errP      = (u16*)p;   p += (size_t)Bc * ESTRIDE * H * 2;
    u16* WoTp      = (u16*)p;   p += (size_t)Bc * N_OUT * H * 2;
    u16* WhhTp     = (u16*)p;   p += (size_t)H * H * 2;
    float* WhhT32  = (float*)p; p += (size_t)H * H * 4;
    float* WoT32   = (float*)p; p += (size_t)N_OUT * H * 4;
    float* WihP    = (float*)p; p += (size_t)N_IN * H * 4;
    float* WhhP    = (float*)p; p += (size_t)H * H * 4;
    float* hp      = (float*)p; p += (size_t)2 * BSZ * H * 4;
    float* radT    = (float*)p; p += (size_t)T_STEPS * BSZ * H * 4;
    float* lam     = (float*)p; p += (size_t)BSZ * H * 4;
    float* de      = (float*)p; p += (size_t)BSZ * H * 4;
    float* head_h  = (float*)p; p += (size_t)BSZ * H * 4;
    float* head_out= (float*)p; p += (size_t)BSZ * N_OUT * 4;
    float* rad_out = (float*)p;

    transpose_k<<<dim3(H / 32, H / 32), 256, 0, stream>>>(Whh, WhhT32, H, H);
    transpose_k<<<dim3(N_OUT / 32, H / 32), 256, 0, stream>>>(Wo, WoT32, H, N_OUT);
    packPairs_k<<<(N_IN * 128) / 256, 256, 0, stream>>>(Wih, WihP);
    packPairs_k<<<(H * 128) / 256, 256, 0, stream>>>(Whh, WhhP);
    packWT_k<<<128, 256, 0, stream>>>(WhhT32, WhhTp);

    for (int b0 = 0; b0 < BSZ; b0 += Bc) {
        prefresh_k<<<dim3(T_STEPS, Bc), 256, 0, stream>>>(
            X + (size_t)b0 * N_IN, eps + b0, Wih, WihP, errP,
            radT + (size_t)b0 * H);
        prep0_k<<<Bc, 256, 0, stream>>>(
            X + (size_t)b0 * N_IN, eps + b0, Wih, bih, bhh, hp + (size_t)b0 * H);
        for (int t = 1; t < T_STEPS; ++t) {
            int E_old = t * (N_IN + H);
            const float* hp_prev = hp + (size_t)((t - 1) & 1) * BSZ * H + (size_t)b0 * H;
            float*       hp_new  = hp + (size_t)(t & 1) * BSZ * H + (size_t)b0 * H;
            const float* rad_prev = radT + (size_t)(t - 1) * BSZ * H + (size_t)b0 * H;
            float*       rad_new  = radT + (size_t)t * BSZ * H + (size_t)b0 * H;
            step_k<<<dim3(GNB + 9, Bc), 256, 0, stream>>>(
                X + (size_t)(t * BSZ + b0) * N_IN, eps + b0, Wih, Whh,
                WhhP, WhhTp, bih, bhh, hp_prev, rad_prev, hp_new, rad_new,
                errP, E_old);
        }
        const float* hp_last = hp + (size_t)((T_STEPS - 1) & 1) * BSZ * H + (size_t)b0 * H;
        const float* rad_last = radT + (size_t)(T_STEPS - 1) * BSZ * H + (size_t)b0 * H;
        tanh_final_k<<<Bc, 256, 0, stream>>>(
            hp_last, rad_last, lam + (size_t)b0 * H, de + (size_t)b0 * H,
            head_h + (size_t)b0 * H);
        packWoT_k<<<Bc, 256, 0, stream>>>(WoT32, lam + (size_t)b0 * H, WoTp);
        head_out_k<<<Bc, 64, 0, stream>>>(
            head_h + (size_t)b0 * H, de + (size_t)b0 * H, Wo, bo,
            head_out + (size_t)b0 * N_OUT, rad_out + (size_t)b0 * N_OUT);
        gemm_out_k<<<dim3(ESTRIDE / 256, Bc), 256, 0, stream>>>(
            errP, WoTp, rad_out + (size_t)b0 * N_OUT);
    }

    combine_k<<<(BSZ * N_OUT + 255) / 256, 256, 0, stream>>>(head_out, rad_out, out);
}

// Round 4
// 2072.953 us; speedup vs baseline: 3.0019x; 1.0066x over previous
//
#include <hip/hip_runtime.h>
#include <math.h>

typedef unsigned short u16;
typedef unsigned long long u64;
typedef __attribute__((ext_vector_type(8))) short bf16x8;   // MFMA A/B frag
typedef __attribute__((ext_vector_type(4))) float f32x4;    // MFMA C/D frag

#define T_STEPS 32
#define BSZ     32
#define N_IN    64
#define H       256
#define N_OUT   64
#define ESTRIDE 9984              // rows = 320*31 + 64 (final fresh block)
#define CLAMP_MIN (-2.0f)
#define CLAMP_MAX ( 2.0f)
#define GNB 16                    // gemm blocks per sample (32-row tiles)

// ---------------------------------------------------------------------------
// Fragment-packed layout "B" (8B-quad granular):
//   element (row R, k):  RT=R>>4, m=R&15, KC=k>>5, qq=(k&31)>>3, h=(k&7)>>2, v=k&3
//   u16 offset = ((RT*8+KC)*4+qq)*128 + m*8 + h*4 + v
// A/B-frag load for (RT,KC), lane(m,q): contiguous 16B at (((RT*8+KC)*4+q)<<7)+m*8.
// Frag element j (j=0..7) corresponds to k = KC*32 + q*8 + j.
// C^T store (operand-swapped mfma): lane's 4 acc values = 8B contiguous.
// ---------------------------------------------------------------------------

__device__ inline u16 f2bf(float x) {                       // RTNE fp32->bf16
    unsigned u = __builtin_bit_cast(unsigned, x);
    unsigned r = u + 0x7FFFu + ((u >> 16) & 1u);
    return (u16)(r >> 16);
}
__device__ inline float bf2f(short s) {
    return __builtin_bit_cast(float, ((unsigned)(u16)s) << 16);
}

__device__ __forceinline__ void gl_lds16(const u16* g, u16* l) {
    __builtin_amdgcn_global_load_lds(
        (const __attribute__((address_space(1))) unsigned int*)g,
        (__attribute__((address_space(3))) unsigned int*)l,
        16, 0, 0);
}

// ---------------------------------------------------------------------------
__global__ void transpose_k(const float* __restrict__ src, float* __restrict__ dst,
                            int R, int C)
{
    __shared__ float tile[32][33];
    int bi = blockIdx.y, bj = blockIdx.x;
    int r0 = threadIdx.x >> 5, c = threadIdx.x & 31;
    #pragma unroll
    for (int rr = 0; rr < 4; ++rr) {
        int r = r0 * 4 + rr;
        tile[r][c] = src[(bi * 32 + r) * C + bj * 32 + c];
    }
    __syncthreads();
    #pragma unroll
    for (int rr = 0; rr < 4; ++rr) {
        int r = r0 * 4 + rr;
        dst[(bj * 32 + r) * R + bi * 32 + c] = tile[c][r];
    }
}

// ---------------------------------------------------------------------------
// packPairs: W (R x 256 fp32) -> float2 pairs in layout-B p-order.
// ---------------------------------------------------------------------------
__global__ void packPairs_k(const float* __restrict__ W, float* __restrict__ WP)
{
    int p = blockIdx.x * 256 + threadIdx.x;
    int vb = (p & 1) * 2, hh = (p >> 1) & 1, m = (p >> 2) & 15, qq = (p >> 6) & 3;
    int KC = (p >> 8) & 7, RT = p >> 11;
    int i = RT * 16 + m, k = KC * 32 + qq * 8 + hh * 4 + vb;
    ((float2*)WP)[p] = make_float2(W[(size_t)i * H + k], W[(size_t)i * H + k + 1]);
}

// ---------------------------------------------------------------------------
// packWT: WhhT32 (256x256 fp32) -> bf16 layout-B (static, no lam). grid 128x256.
// ---------------------------------------------------------------------------
__global__ void packWT_k(const float* __restrict__ WT32, u16* __restrict__ WTp)
{
    int p = blockIdx.x * 256 + threadIdx.x;     // p < 32768
    int vb = (p & 1) * 2, hh = (p >> 1) & 1, m = (p >> 2) & 15, qq = (p >> 6) & 3;
    int KC = (p >> 8) & 7, RT = p >> 11;
    int n = RT * 16 + m, k = KC * 32 + qq * 8 + hh * 4 + vb;
    *(unsigned*)&WTp[2 * p] =
          (unsigned)f2bf(WT32[(size_t)n * H + k])
        | ((unsigned)f2bf(WT32[(size_t)n * H + k + 1]) << 16);
}

// ---------------------------------------------------------------------------
// prefresh: fresh rows (rho_t * Wih) for ALL t + fresh-rad baseline (plain
// store — first writer of radT[t]) + (t==0) head preactivation hp0.
// grid (T_STEPS, Bc).
// ---------------------------------------------------------------------------
__global__ __launch_bounds__(256) void prefresh_k(
    const float* __restrict__ X, const float* __restrict__ eps,
    const float* __restrict__ Wih, const float* __restrict__ WihP,
    const float* __restrict__ bih, const float* __restrict__ bhh,
    u16* __restrict__ err, float* __restrict__ radT, float* __restrict__ hp0)
{
    __shared__ float rho_s[N_IN], hx_s[N_IN];
    const int t = blockIdx.x, bi = blockIdx.y, tid = threadIdx.x;
    if (tid < N_IN) {
        float x = X[((size_t)t * BSZ + bi) * N_IN + tid], e = eps[bi];
        float lo = fmaxf(x - e, CLAMP_MIN), up = fminf(x + e, CLAMP_MAX);
        rho_s[tid] = 0.5f * (up - lo);
        hx_s[tid]  = 0.5f * (up + lo);
    }
    __syncthreads();

    // fresh-rad: column GEMV, coalesced cached loads, no atomics
    float s = 0.f;
    #pragma unroll 8
    for (int i = 0; i < N_IN; ++i)
        s += fabsf(rho_s[i]) * fabsf(Wih[(size_t)i * H + tid]);
    radT[(size_t)t * BSZ * H + (size_t)bi * H + tid] = s;

    if (t == 0) {                               // absorb prep0
        float acc = bih[tid] + bhh[tid];
        #pragma unroll 8
        for (int i = 0; i < N_IN; ++i) acc += hx_s[i] * Wih[i * H + tid];
        hp0[bi * H + tid] = acc;
    }

    u16* dst = err + (size_t)bi * ESTRIDE * H + (size_t)(20 * t) * 4096; // row 320t
    const float2* wp = (const float2*)WihP;
    #pragma unroll 4
    for (int iter = 0; iter < 32; ++iter) {
        int p = iter * 256 + tid;
        int i = (p >> 11) * 16 + ((p >> 2) & 15);
        float2 w = wp[p];
        float rho = rho_s[i];
        *(unsigned*)&dst[2 * p] =
            (unsigned)f2bf(rho * w.x) | ((unsigned)f2bf(rho * w.y) << 16);
    }
}

// ---------------------------------------------------------------------------
// step_k: ONE launch per timestep. grid (GNB+9, Bc).
//   bx <  GNB : gemm role — 32-row tiles, FOUR 16KB LDS buffers, stage issued
//               3 tiles ahead via global_load_lds, uniform counted vmcnt(16)
//               + raw barrier per tile (stage needed next iter is >=17 deep
//               in the queue -> always drained; issue-depth ~3 iters hides
//               HBM latency). B-slab = static bf16 WhhTp frags scaled
//               in-registers by lam. C^T direct coalesced stores.
//   bx == GNB : head role — hp_new GEMV.
//   bx >  GNB : diag roles (8) — diag rows (coalesced WhhP float2) +
//               diag-rad column GEMV slice.
// ---------------------------------------------------------------------------
__global__ __launch_bounds__(256, 2) void step_k(
    const float* __restrict__ Xt, const float* __restrict__ eps,
    const float* __restrict__ Wih, const float* __restrict__ Whh,
    const float* __restrict__ WhhP, const u16* __restrict__ WhhTp,
    const float* __restrict__ bih, const float* __restrict__ bhh,
    const float* __restrict__ hp_prev, const float* __restrict__ rad_prev,
    float* __restrict__ hp_new, float* __restrict__ rad_new,
    u16* __restrict__ err, int E_old)
{
    __shared__ u16 sbuf[4][8192];            // 4 x 16KB tile buffers
    __shared__ float smf[H];                 // lam / de / head-vals per role
    const int bx = blockIdx.x, b = blockIdx.y, tid = threadIdx.x;

    if (bx < GNB) {
        const int ntiles = (E_old - H) >> 5;             // 32-row tiles = 10t-8
        if (bx >= ntiles) return;
        u16* errB = err + (size_t)b * ESTRIDE * H;
        const int wave = tid >> 6, lane = tid & 63;
        const int m = lane & 15, q = lane >> 4;

        // prologue: stage up to 3 tiles (fly under tanh + B-load/fold)
        #pragma unroll
        for (int j = 0; j < 3; ++j) {
            int tj = bx + j * GNB;
            if (tj < ntiles) {
                const u16* g = errB + (size_t)tj * 8192;
                #pragma unroll
                for (int r = 0; r < 4; ++r)
                    gl_lds16(g + r * 2048 + tid * 8, &sbuf[j][r * 2048 + wave * 512]);
            }
        }

        // B-slab: static bf16 WhhTp frags (L2-hot, shared by all blocks/samples)
        bf16x8 bf[4][8];
        #pragma unroll
        for (int nt = 0; nt < 4; ++nt)
            #pragma unroll
            for (int kc = 0; kc < 8; ++kc)
                bf[nt][kc] = *(const bf16x8*)
                    &WhhTp[(size_t)(((((wave * 4 + nt) * 8 + kc) * 4 + q) << 7) + m * 8)];

        { // lam -> smf
            float hd = hp_prev[b * H + tid], rv = rad_prev[b * H + tid];
            float lo = hd - rv, up = hd + rv;
            float tl = tanhf(lo), tu = tanhf(up);
            smf[tid] = fminf(1.f - tl * tl, 1.f - tu * tu);
        }
        asm volatile("s_waitcnt lgkmcnt(0)" ::: "memory");
        __builtin_amdgcn_s_barrier();        // lam visible (vm loads still flying)

        // fold lam into B-frags in-register (one-time per block)
        #pragma unroll
        for (int nt = 0; nt < 4; ++nt)
            #pragma unroll
            for (int kc = 0; kc < 8; ++kc) {
                const int k0 = kc * 32 + q * 8;
                float4 la = *(const float4*)&smf[k0];
                float4 lb = *(const float4*)&smf[k0 + 4];
                bf16x8 w = bf[nt][kc], f;
                f[0] = (short)f2bf(bf2f(w[0]) * la.x);
                f[1] = (short)f2bf(bf2f(w[1]) * la.y);
                f[2] = (short)f2bf(bf2f(w[2]) * la.z);
                f[3] = (short)f2bf(bf2f(w[3]) * la.w);
                f[4] = (short)f2bf(bf2f(w[4]) * lb.x);
                f[5] = (short)f2bf(bf2f(w[5]) * lb.y);
                f[6] = (short)f2bf(bf2f(w[6]) * lb.z);
                f[7] = (short)f2bf(bf2f(w[7]) * lb.w);
                bf[nt][kc] = f;
            }

        float racc[16];
        #pragma unroll
        for (int i = 0; i < 16; ++i) racc[i] = 0.f;

        // own stage loads fully drained, then sync -> buf0..2 valid for all
        asm volatile("s_waitcnt vmcnt(0)" ::: "memory");
        __builtin_amdgcn_s_barrier();

        int cur = 0;
        for (int tile = bx; tile < ntiles; tile += GNB) {
            int pf = tile + 3 * GNB;
            if (pf < ntiles) {               // stage 3 tiles ahead
                const u16* g = errB + (size_t)pf * 8192;
                #pragma unroll
                for (int r = 0; r < 4; ++r)
                    gl_lds16(g + r * 2048 + tid * 8,
                             &sbuf[(cur + 3) & 3][r * 2048 + wave * 512]);
            }

            f32x4 acc[2][4];
            #pragma unroll
            for (int i = 0; i < 2; ++i)
                #pragma unroll
                for (int c = 0; c < 4; ++c) acc[i][c] = (f32x4){0.f, 0.f, 0.f, 0.f};

            #pragma unroll
            for (int kc = 0; kc < 8; ++kc) {
                bf16x8 af[2];
                #pragma unroll
                for (int rt = 0; rt < 2; ++rt)
                    af[rt] = *(const bf16x8*)
                        &sbuf[cur][(((rt * 8 + kc) * 4 + q) << 7) + m * 8];
                #pragma unroll
                for (int nt = 0; nt < 4; ++nt)
                    #pragma unroll
                    for (int rt = 0; rt < 2; ++rt)   // swapped: A=WT, B=err -> C^T
                        acc[rt][nt] = __builtin_amdgcn_mfma_f32_16x16x32_bf16(
                            bf[nt][kc], af[rt], acc[rt][nt], 0, 0, 0);
            }

            // C^T store: lane holds err-row r = rt*16+m, n = NT*16+q*4+v
            #pragma unroll
            for (int rt = 0; rt < 2; ++rt) {
                const size_t rowbase = (size_t)(tile * 2 + rt) * 4096;
                #pragma unroll
                for (int nt = 0; nt < 4; ++nt) {
                    f32x4 v = acc[rt][nt];
                    racc[nt * 4 + 0] += fabsf(v[0]);
                    racc[nt * 4 + 1] += fabsf(v[1]);
                    racc[nt * 4 + 2] += fabsf(v[2]);
                    racc[nt * 4 + 3] += fabsf(v[3]);
                    unsigned lo = (unsigned)f2bf(v[0]) | ((unsigned)f2bf(v[1]) << 16);
                    unsigned hi = (unsigned)f2bf(v[2]) | ((unsigned)f2bf(v[3]) << 16);
                    const int NT  = wave * 4 + nt;
                    const int kcs = NT >> 1;
                    const int qq  = (NT & 1) * 2 + (q >> 1);
                    const size_t off16 = rowbase
                        + (size_t)(((kcs * 4 + qq) << 7) + m * 8 + (q & 1) * 4);
                    *(u64*)&errB[off16] = ((u64)hi << 32) | lo;
                }
            }
            // newest 16 = this iter's 4 stage loads + 8 stores (+slack);
            // the stage consumed next iter is >=17 deep -> guaranteed drained.
            asm volatile("s_waitcnt vmcnt(16)" ::: "memory");
            __builtin_amdgcn_s_barrier();
            cur = (cur + 1) & 3;
        }

        // rad: reduce over 16 m-lanes, one atomic per n from m==0 lanes
        #pragma unroll
        for (int i = 0; i < 16; ++i) {
            float v = racc[i];
            v += __shfl_xor(v, 1);
            v += __shfl_xor(v, 2);
            v += __shfl_xor(v, 4);
            v += __shfl_xor(v, 8);
            if (m == 0) {
                int nt = i >> 2, vv = i & 3;
                atomicAdd(&rad_new[b * H + wave * 64 + nt * 16 + q * 4 + vv], v);
            }
        }
        return;
    }

    // ---- aux roles: shared tanh transform ----
    float hd = hp_prev[b * H + tid], rv = rad_prev[b * H + tid];
    float lo = hd - rv, up = hd + rv;
    float tl = tanhf(lo), tu = tanhf(up);
    float la = fminf(1.f - tl * tl, 1.f - tu * tu);
    float mu = 0.5f * (tu + tl - la * (up + lo));
    float dd = 0.5f * (tu - tl - la * (up - lo));

    if (bx == GNB) {                         // head role: hp_new GEMV
        float* hv  = smf;
        float* hxr = (float*)sbuf;
        hv[tid] = la * hd + mu;
        if (tid < N_IN) {
            float x = Xt[b * N_IN + tid], e = eps[b];
            float l2 = fmaxf(x - e, CLAMP_MIN), u2 = fminf(x + e, CLAMP_MAX);
            hxr[tid] = 0.5f * (l2 + u2);
        }
        __syncthreads();
        float acc = bih[tid] + bhh[tid];
        #pragma unroll 8
        for (int i = 0; i < N_IN; ++i) acc += hxr[i] * Wih[i * H + tid];
        #pragma unroll 8
        for (int j = 0; j < H; ++j) acc += hv[j] * Whh[j * H + tid];
        hp_new[b * H + tid] = acc;
        return;
    }

    // diag roles: rrole in [0,8), rows [rrole*32, rrole*32+32) of diag block
    const int rrole = bx - GNB - 1;
    float* de_s = smf;
    de_s[tid] = dd;
    __syncthreads();
    u16* errB = err + (size_t)b * ESTRIDE * H;
    const size_t diagBase = (size_t)((E_old - H) >> 4) * 4096;
    const float2* wp = (const float2*)WhhP;
    #pragma unroll 4
    for (int iter = 0; iter < 16; ++iter) {
        int p = (rrole * 16 + iter) * 256 + tid;
        int i = (p >> 11) * 16 + ((p >> 2) & 15);
        float2 w = wp[p];
        float dv = de_s[i];
        *(unsigned*)&errB[diagBase + 2 * p] =
            (unsigned)f2bf(dv * w.x) | ((unsigned)f2bf(dv * w.y) << 16);
    }
    // diag-rad slice: column GEMV over this role's 32 rows
    float s = 0.f;
    #pragma unroll 8
    for (int ii = 0; ii < 32; ++ii) {
        int i = rrole * 32 + ii;
        s += fabsf(de_s[i]) * fabsf(Whh[(size_t)i * H + tid]);
    }
    atomicAdd(&rad_new[b * H + tid], s);
}

// ---------------------------------------------------------------------------
__global__ __launch_bounds__(256) void tanh_final_k(
    const float* __restrict__ hp, const float* __restrict__ rad,
    float* __restrict__ lam, float* __restrict__ de, float* __restrict__ head_h)
{
    const int b = blockIdx.x, h = threadIdx.x;
    float hd = hp[b * H + h], r = rad[b * H + h];
    float l = hd - r, u = hd + r;
    float tl = tanhf(l), tu = tanhf(u);
    float la = fminf(1.f - tl * tl, 1.f - tu * tu);
    float mu = 0.5f * (tu + tl - la * (u + l));
    float dd = 0.5f * (tu - tl - la * (u - l));
    lam[b * H + h] = la;
    de[b * H + h]  = dd;
    head_h[b * H + h] = la * hd + mu;
}

// ---------------------------------------------------------------------------
// pack WoT frag-packed (layout B), lam folded. grid Bc x 256.
// ---------------------------------------------------------------------------
__global__ __launch_bounds__(256) void packWoT_k(
    const float* __restrict__ WoT32, const float* __restrict__ lam,
    u16* __restrict__ WoTp)
{
    const int b = blockIdx.x, tid = threadIdx.x;
    __shared__ float lam_s[H];
    lam_s[tid] = lam[b * H + tid];
    __syncthreads();
    u16* dst = WoTp + (size_t)b * N_OUT * H;
    #pragma unroll 4
    for (int iter = 0; iter < 32; ++iter) {
        int p = iter * 256 + tid;
        int vb = (p & 1) * 2, hh = (p >> 1) & 1, m = (p >> 2) & 15, qq = (p >> 6) & 3;
        int KC = (p >> 8) & 7, RT = p >> 11;   // RT < 4
        int n = RT * 16 + m, k = KC * 32 + qq * 8 + hh * 4 + vb;
        *(unsigned*)&dst[2 * p] =
              (unsigned)f2bf(lam_s[k]     * WoT32[(size_t)n * H + k])
            | ((unsigned)f2bf(lam_s[k + 1] * WoT32[(size_t)n * H + k + 1]) << 16);
    }
}

// ---------------------------------------------------------------------------
__global__ void head_out_k(
    const float* __restrict__ head_h, const float* __restrict__ de,
    const float* __restrict__ Wo, const float* __restrict__ bo,
    float* __restrict__ head_out, float* __restrict__ rad_out)
{
    const int b = blockIdx.x, o = threadIdx.x;
    float acc = bo[o], accR = 0.f;
    #pragma unroll 4
    for (int j = 0; j < H; ++j) {
        float w = Wo[j * N_OUT + o];
        acc  += head_h[b * H + j] * w;
        accR += fabsf(de[b * H + j] * w);
    }
    head_out[b * N_OUT + o] = acc;
    rad_out[b * N_OUT + o]  = accR;
}

// ---------------------------------------------------------------------------
// final radius: rad_out += sum_rows |err @ WoTp^T| over all ESTRIDE rows.
// ---------------------------------------------------------------------------
__global__ __launch_bounds__(256) void gemm_out_k(
    const u16* __restrict__ err, const u16* __restrict__ WoTp,
    float* __restrict__ rad_out)
{
    __shared__ float rad_s[N_OUT];
    const int b = blockIdx.y, row0 = blockIdx.x * 256, tid = threadIdx.x;
    const int wave = tid >> 6, lane = tid & 63;
    const int m = lane & 15, q = lane >> 4;
    const u16* errB = err + (size_t)b * ESTRIDE * H;
    const u16* Wb   = WoTp + (size_t)b * N_OUT * H;

    if (tid < N_OUT) rad_s[tid] = 0.f;
    __syncthreads();

    f32x4 acc[4][4];
    #pragma unroll
    for (int i = 0; i < 4; ++i)
        #pragma unroll
        for (int c = 0; c < 4; ++c) acc[i][c] = (f32x4){0.f, 0.f, 0.f, 0.f};

    const int tile0 = (row0 >> 4) + wave * 4;
    #pragma unroll
    for (int kc = 0; kc < 8; ++kc) {
        bf16x8 af[4], bw[4];
        #pragma unroll
        for (int rt = 0; rt < 4; ++rt)
            af[rt] = *(const bf16x8*)
                &errB[(size_t)(((((tile0 + rt) * 8 + kc) * 4 + q) << 7) + m * 8)];
        #pragma unroll
        for (int nt = 0; nt < 4; ++nt)
            bw[nt] = *(const bf16x8*)
                &Wb[(size_t)((((nt * 8 + kc) * 4 + q) << 7) + m * 8)];
        #pragma unroll
        for (int nt = 0; nt < 4; ++nt)
            #pragma unroll
            for (int rt = 0; rt < 4; ++rt)
                acc[rt][nt] = __builtin_amdgcn_mfma_f32_16x16x32_bf16(
                    af[rt], bw[nt], acc[rt][nt], 0, 0, 0);
    }
    #pragma unroll
    for (int nt = 0; nt < 4; ++nt) {
        float s = 0.f;
        #pragma unroll
        for (int rt = 0; rt < 4; ++rt)
            #pragma unroll
            for (int r = 0; r < 4; ++r) s += fabsf(acc[rt][nt][r]);
        atomicAdd(&rad_s[nt * 16 + m], s);
    }
    __syncthreads();
    if (tid < N_OUT) atomicAdd(&rad_out[b * N_OUT + tid], rad_s[tid]);
}

// ---------------------------------------------------------------------------
__global__ void combine_k(const float* __restrict__ head_out,
                          const float* __restrict__ rad_out,
                          float* __restrict__ out)
{
    int i = blockIdx.x * 256 + threadIdx.x;
    if (i < BSZ * N_OUT) {
        float h = head_out[i], r = rad_out[i];
        out[i]               = h - r;
        out[BSZ * N_OUT + i] = h + r;
    }
}

// ---------------------------------------------------------------------------
extern "C" void kernel_launch(void* const* d_in, const int* in_sizes, int n_in,
                              void* d_out, int out_size, void* d_ws, size_t ws_size,
                              hipStream_t stream)
{
    const float* X    = (const float*)d_in[0];
    const float* eps  = (const float*)d_in[1];
    const float* Wih  = (const float*)d_in[2];
    const float* Whh  = (const float*)d_in[3];
    const float* bih  = (const float*)d_in[4];
    const float* bhh  = (const float*)d_in[5];
    const float* Wo   = (const float*)d_in[6];
    const float* bo   = (const float*)d_in[7];
    float* out = (float*)d_out;

    const size_t per_sample = (size_t)ESTRIDE * H * 2 + (size_t)N_OUT * H * 2;
    const size_t shared_b = (size_t)H * H * 4       // WhhT32
                          + (size_t)N_OUT * H * 4   // WoT32
                          + (size_t)N_IN * H * 4    // WihP
                          + (size_t)H * H * 4       // WhhP
                          + (size_t)H * H * 2       // WhhTp
                          + (size_t)2 * BSZ * H * 4                      // hp[2]
                          + (size_t)T_STEPS * BSZ * H * 4                // radT
                          + (size_t)3 * BSZ * H * 4                      // lam/de/head_h
                          + (size_t)2 * BSZ * N_OUT * 4 + 256;
    int Bc = BSZ;
    while (Bc > 1 && (size_t)Bc * per_sample + shared_b > ws_size) Bc >>= 1;

    char* p = (char*)d_ws;
    u16* errP      = (u16*)p;   p += (size_t)Bc * ESTRIDE * H * 2;
    u16* WoTp      = (u16*)p;   p += (size_t)Bc * N_OUT * H * 2;
    u16* WhhTp     = (u16*)p;   p += (size_t)H * H * 2;
    float* WhhT32  = (float*)p; p += (size_t)H * H * 4;
    float* WoT32   = (float*)p; p += (size_t)N_OUT * H * 4;
    float* WihP    = (float*)p; p += (size_t)N_IN * H * 4;
    float* WhhP    = (float*)p; p += (size_t)H * H * 4;
    float* hp      = (float*)p; p += (size_t)2 * BSZ * H * 4;
    float* radT    = (float*)p; p += (size_t)T_STEPS * BSZ * H * 4;
    float* lam     = (float*)p; p += (size_t)BSZ * H * 4;
    float* de      = (float*)p; p += (size_t)BSZ * H * 4;
    float* head_h  = (float*)p; p += (size_t)BSZ * H * 4;
    float* head_out= (float*)p; p += (size_t)BSZ * N_OUT * 4;
    float* rad_out = (float*)p;

    transpose_k<<<dim3(H / 32, H / 32), 256, 0, stream>>>(Whh, WhhT32, H, H);
    transpose_k<<<dim3(N_OUT / 32, H / 32), 256, 0, stream>>>(Wo, WoT32, H, N_OUT);
    packPairs_k<<<(N_IN * 128) / 256, 256, 0, stream>>>(Wih, WihP);
    packPairs_k<<<(H * 128) / 256, 256, 0, stream>>>(Whh, WhhP);
    packWT_k<<<128, 256, 0, stream>>>(WhhT32, WhhTp);

    for (int b0 = 0; b0 < BSZ; b0 += Bc) {
        prefresh_k<<<dim3(T_STEPS, Bc), 256, 0, stream>>>(
            X + (size_t)b0 * N_IN, eps + b0, Wih, WihP, bih, bhh, errP,
            radT + (size_t)b0 * H, hp + (size_t)b0 * H);
        for (int t = 1; t < T_STEPS; ++t) {
            int E_old = t * (N_IN + H);
            const float* hp_prev = hp + (size_t)((t - 1) & 1) * BSZ * H + (size_t)b0 * H;
            float*       hp_new  = hp + (size_t)(t & 1) * BSZ * H + (size_t)b0 * H;
            const float* rad_prev = radT + (size_t)(t - 1) * BSZ * H + (size_t)b0 * H;
            float*       rad_new  = radT + (size_t)t * BSZ * H + (size_t)b0 * H;
            step_k<<<dim3(GNB + 9, Bc), 256, 0, stream>>>(
                X + (size_t)(t * BSZ + b0) * N_IN, eps + b0, Wih, Whh,
                WhhP, WhhTp, bih, bhh, hp_prev, rad_prev, hp_new, rad_new,
                errP, E_old);
        }
        const float* hp_last = hp + (size_t)((T_STEPS - 1) & 1) * BSZ * H + (size_t)b0 * H;
        const float* rad_last = radT + (size_t)(T_STEPS - 1) * BSZ * H + (size_t)b0 * H;
        tanh_final_k<<<Bc, 256, 0, stream>>>(
            hp_last, rad_last, lam + (size_t)b0 * H, de + (size_t)b0 * H,
            head_h + (size_t)b0 * H);
        packWoT_k<<<Bc, 256, 0, stream>>>(WoT32, lam + (size_t)b0 * H, WoTp);
        head_out_k<<<Bc, 64, 0, stream>>>(
            head_h + (size_t)b0 * H, de + (size_t)b0 * H, Wo, bo,
            head_out + (size_t)b0 * N_OUT, rad_out + (size_t)b0 * N_OUT);
        gemm_out_k<<<dim3(ESTRIDE / 256, Bc), 256, 0, stream>>>(
            errP, WoTp, rad_out + (size_t)b0 * N_OUT);
    }

    combine_k<<<(BSZ * N_OUT + 255) / 256, 256, 0, stream>>>(head_out, rad_out, out);
}

// Round 5
// 1671.559 us; speedup vs baseline: 3.7227x; 1.2401x over previous
//
#include <hip/hip_runtime.h>
#include <math.h>

typedef unsigned short u16;
typedef unsigned long long u64;
typedef __attribute__((ext_vector_type(8))) short bf16x8;   // MFMA A/B frag
typedef __attribute__((ext_vector_type(4))) float f32x4;    // MFMA C/D frag

#define T_STEPS 32
#define BSZ     32
#define N_IN    64
#define H       256
#define N_OUT   64
#define ESTRIDE 9984              // rows = 320*31 + 64 (final fresh block)
#define CLAMP_MIN (-2.0f)
#define CLAMP_MAX ( 2.0f)
#define GNB 16                    // gemm blocks per sample (32-row tiles)

// ---------------------------------------------------------------------------
// Fragment-packed layout "B" (8B-quad granular):
//   element (row R, k):  RT=R>>4, m=R&15, KC=k>>5, qq=(k&31)>>3, h=(k&7)>>2, v=k&3
//   u16 offset = ((RT*8+KC)*4+qq)*128 + m*8 + h*4 + v
// A/B-frag load for (RT,KC), lane(m,q): contiguous 16B at (((RT*8+KC)*4+q)<<7)+m*8.
// C^T store (operand-swapped mfma): lane's 4 acc values = 8B contiguous.
// ---------------------------------------------------------------------------

__device__ inline u16 f2bf(float x) {                       // RTNE fp32->bf16
    unsigned u = __builtin_bit_cast(unsigned, x);
    unsigned r = u + 0x7FFFu + ((u >> 16) & 1u);
    return (u16)(r >> 16);
}
__device__ inline float bf2f(short s) {
    return __builtin_bit_cast(float, ((unsigned)(u16)s) << 16);
}

__device__ __forceinline__ void gl_lds16(const u16* g, u16* l) {
    __builtin_amdgcn_global_load_lds(
        (const __attribute__((address_space(1))) unsigned int*)g,
        (__attribute__((address_space(3))) unsigned int*)l,
        16, 0, 0);
}

// ---------------------------------------------------------------------------
__global__ void transpose_k(const float* __restrict__ src, float* __restrict__ dst,
                            int R, int C)
{
    __shared__ float tile[32][33];
    int bi = blockIdx.y, bj = blockIdx.x;
    int r0 = threadIdx.x >> 5, c = threadIdx.x & 31;
    #pragma unroll
    for (int rr = 0; rr < 4; ++rr) {
        int r = r0 * 4 + rr;
        tile[r][c] = src[(bi * 32 + r) * C + bj * 32 + c];
    }
    __syncthreads();
    #pragma unroll
    for (int rr = 0; rr < 4; ++rr) {
        int r = r0 * 4 + rr;
        dst[(bj * 32 + r) * R + bi * 32 + c] = tile[c][r];
    }
}

// ---------------------------------------------------------------------------
// packPairs: W (R x 256 fp32) -> float2 pairs in layout-B p-order.
// ---------------------------------------------------------------------------
__global__ void packPairs_k(const float* __restrict__ W, float* __restrict__ WP)
{
    int p = blockIdx.x * 256 + threadIdx.x;
    int vb = (p & 1) * 2, hh = (p >> 1) & 1, m = (p >> 2) & 15, qq = (p >> 6) & 3;
    int KC = (p >> 8) & 7, RT = p >> 11;
    int i = RT * 16 + m, k = KC * 32 + qq * 8 + hh * 4 + vb;
    ((float2*)WP)[p] = make_float2(W[(size_t)i * H + k], W[(size_t)i * H + k + 1]);
}

// ---------------------------------------------------------------------------
// packWT: WhhT32 (256x256 fp32) -> bf16 layout-B (static, no lam). grid 128x256.
// ---------------------------------------------------------------------------
__global__ void packWT_k(const float* __restrict__ WT32, u16* __restrict__ WTp)
{
    int p = blockIdx.x * 256 + threadIdx.x;     // p < 32768
    int vb = (p & 1) * 2, hh = (p >> 1) & 1, m = (p >> 2) & 15, qq = (p >> 6) & 3;
    int KC = (p >> 8) & 7, RT = p >> 11;
    int n = RT * 16 + m, k = KC * 32 + qq * 8 + hh * 4 + vb;
    *(unsigned*)&WTp[2 * p] =
          (unsigned)f2bf(WT32[(size_t)n * H + k])
        | ((unsigned)f2bf(WT32[(size_t)n * H + k + 1]) << 16);
}

// ---------------------------------------------------------------------------
// prefresh: fresh rows (rho_t * Wih) for ALL t + fresh-rad baseline (plain
// store — first writer of radT[t]) + (t==0) head preactivation hp0.
// grid (T_STEPS, Bc).
// ---------------------------------------------------------------------------
__global__ __launch_bounds__(256) void prefresh_k(
    const float* __restrict__ X, const float* __restrict__ eps,
    const float* __restrict__ Wih, const float* __restrict__ WihP,
    const float* __restrict__ bih, const float* __restrict__ bhh,
    u16* __restrict__ err, float* __restrict__ radT, float* __restrict__ hp0)
{
    __shared__ float rho_s[N_IN], hx_s[N_IN];
    const int t = blockIdx.x, bi = blockIdx.y, tid = threadIdx.x;
    if (tid < N_IN) {
        float x = X[((size_t)t * BSZ + bi) * N_IN + tid], e = eps[bi];
        float lo = fmaxf(x - e, CLAMP_MIN), up = fminf(x + e, CLAMP_MAX);
        rho_s[tid] = 0.5f * (up - lo);
        hx_s[tid]  = 0.5f * (up + lo);
    }
    __syncthreads();

    // fresh-rad: column GEMV, coalesced cached loads, no atomics
    float s = 0.f;
    #pragma unroll 8
    for (int i = 0; i < N_IN; ++i)
        s += fabsf(rho_s[i]) * fabsf(Wih[(size_t)i * H + tid]);
    radT[(size_t)t * BSZ * H + (size_t)bi * H + tid] = s;

    if (t == 0) {                               // absorb prep0
        float acc = bih[tid] + bhh[tid];
        #pragma unroll 8
        for (int i = 0; i < N_IN; ++i) acc += hx_s[i] * Wih[i * H + tid];
        hp0[bi * H + tid] = acc;
    }

    u16* dst = err + (size_t)bi * ESTRIDE * H + (size_t)(20 * t) * 4096; // row 320t
    const float2* wp = (const float2*)WihP;
    #pragma unroll 4
    for (int iter = 0; iter < 32; ++iter) {
        int p = iter * 256 + tid;
        int i = (p >> 11) * 16 + ((p >> 2) & 15);
        float2 w = wp[p];
        float rho = rho_s[i];
        *(unsigned*)&dst[2 * p] =
            (unsigned)f2bf(rho * w.x) | ((unsigned)f2bf(rho * w.y) << 16);
    }
}

// ---------------------------------------------------------------------------
// step_k: ONE launch per timestep. grid EXACTLY (GNB, Bc) = 512 blocks =
// full residency at 2 blocks/CU (no scheduling waves).
//   All blocks: tanh transform -> lam/de/hh in LDS.
//   bx < ntiles: gemm — 32-row tiles, 4x16KB LDS ring, stage issued 3 tiles
//     ahead, counted s_waitcnt vmcnt(32) per iter (drains exactly
//     stage_{j-3}, keeps 2 iters of stage + 3 iters of stores in flight).
//     B-slab = static bf16 WhhTp frags scaled in-registers by lam.
//     C^T direct coalesced global stores; rad in regs, reduced at end.
//   Epilogue (all blocks): 16 diag rows + diag-rad slice per block;
//     block GNB-1 additionally does the head GEMV.
// ---------------------------------------------------------------------------
__global__ __launch_bounds__(256, 2) void step_k(
    const float* __restrict__ Xt, const float* __restrict__ eps,
    const float* __restrict__ Wih, const float* __restrict__ Whh,
    const float* __restrict__ WhhP, const u16* __restrict__ WhhTp,
    const float* __restrict__ bih, const float* __restrict__ bhh,
    const float* __restrict__ hp_prev, const float* __restrict__ rad_prev,
    float* __restrict__ hp_new, float* __restrict__ rad_new,
    u16* __restrict__ err, int E_old)
{
    __shared__ u16 sbuf[4][8192];            // 4 x 16KB tile ring
    __shared__ float lam_s[H], de_s[H], hh_s[H], hx_s[N_IN];
    const int bx = blockIdx.x, b = blockIdx.y, tid = threadIdx.x;
    const int ntiles = (E_old - H) >> 5;     // 32-row tiles = 10t-8
    u16* errB = err + (size_t)b * ESTRIDE * H;
    const int wave = tid >> 6, lane = tid & 63;
    const int m = lane & 15, q = lane >> 4;
    const bool gem = (bx < ntiles);

    if (gem) {                               // stage up to 3 tiles early
        #pragma unroll
        for (int j = 0; j < 3; ++j) {
            int tj = bx + j * GNB;
            if (tj < ntiles) {
                const u16* g = errB + (size_t)tj * 8192;
                #pragma unroll
                for (int r = 0; r < 4; ++r)
                    gl_lds16(g + r * 2048 + tid * 8, &sbuf[j][r * 2048 + wave * 512]);
            }
        }
    }

    // B-slab: static bf16 WhhTp frags (L2-hot, shared by all blocks/samples)
    bf16x8 bf[4][8];
    if (gem) {
        #pragma unroll
        for (int nt = 0; nt < 4; ++nt)
            #pragma unroll
            for (int kc = 0; kc < 8; ++kc)
                bf[nt][kc] = *(const bf16x8*)
                    &WhhTp[(size_t)(((((wave * 4 + nt) * 8 + kc) * 4 + q) << 7) + m * 8)];
    }

    { // tanh transform -> lam/de/hh (all blocks)
        float hd = hp_prev[b * H + tid], rv = rad_prev[b * H + tid];
        float lo = hd - rv, up = hd + rv;
        float tl = tanhf(lo), tu = tanhf(up);
        float la = fminf(1.f - tl * tl, 1.f - tu * tu);
        float mu = 0.5f * (tu + tl - la * (up + lo));
        float dd = 0.5f * (tu - tl - la * (up - lo));
        lam_s[tid] = la;
        de_s[tid]  = dd;
        hh_s[tid]  = la * hd + mu;
    }
    asm volatile("s_waitcnt lgkmcnt(0)" ::: "memory");
    __builtin_amdgcn_s_barrier();            // LDS visible (vm loads still flying)

    if (gem) {
        // fold lam into B-frags in-register (one-time per block)
        #pragma unroll
        for (int nt = 0; nt < 4; ++nt)
            #pragma unroll
            for (int kc = 0; kc < 8; ++kc) {
                const int k0 = kc * 32 + q * 8;
                float4 la = *(const float4*)&lam_s[k0];
                float4 lb = *(const float4*)&lam_s[k0 + 4];
                bf16x8 w = bf[nt][kc], f;
                f[0] = (short)f2bf(bf2f(w[0]) * la.x);
                f[1] = (short)f2bf(bf2f(w[1]) * la.y);
                f[2] = (short)f2bf(bf2f(w[2]) * la.z);
                f[3] = (short)f2bf(bf2f(w[3]) * la.w);
                f[4] = (short)f2bf(bf2f(w[4]) * lb.x);
                f[5] = (short)f2bf(bf2f(w[5]) * lb.y);
                f[6] = (short)f2bf(bf2f(w[6]) * lb.z);
                f[7] = (short)f2bf(bf2f(w[7]) * lb.w);
                bf[nt][kc] = f;
            }

        float racc[16];
        #pragma unroll
        for (int i = 0; i < 16; ++i) racc[i] = 0.f;

        // own prologue stages drained, then sync -> buf0..2 valid for all waves
        asm volatile("s_waitcnt vmcnt(0)" ::: "memory");
        __builtin_amdgcn_s_barrier();

        int cur = 0;
        for (int tile = bx; tile < ntiles; tile += GNB) {
            int pf = tile + 3 * GNB;
            if (pf < ntiles) {               // stage 3 tiles ahead
                const u16* g = errB + (size_t)pf * 8192;
                #pragma unroll
                for (int r = 0; r < 4; ++r)
                    gl_lds16(g + r * 2048 + tid * 8,
                             &sbuf[(cur + 3) & 3][r * 2048 + wave * 512]);
            }

            f32x4 acc[2][4];
            #pragma unroll
            for (int i = 0; i < 2; ++i)
                #pragma unroll
                for (int c = 0; c < 4; ++c) acc[i][c] = (f32x4){0.f, 0.f, 0.f, 0.f};

            #pragma unroll
            for (int kc = 0; kc < 8; ++kc) {
                bf16x8 af[2];
                #pragma unroll
                for (int rt = 0; rt < 2; ++rt)
                    af[rt] = *(const bf16x8*)
                        &sbuf[cur][(((rt * 8 + kc) * 4 + q) << 7) + m * 8];
                #pragma unroll
                for (int nt = 0; nt < 4; ++nt)
                    #pragma unroll
                    for (int rt = 0; rt < 2; ++rt)   // swapped: A=WT, B=err -> C^T
                        acc[rt][nt] = __builtin_amdgcn_mfma_f32_16x16x32_bf16(
                            bf[nt][kc], af[rt], acc[rt][nt], 0, 0, 0);
            }

            // C^T store: lane holds err-row r = rt*16+m, n = NT*16+q*4+v
            #pragma unroll
            for (int rt = 0; rt < 2; ++rt) {
                const size_t rowbase = (size_t)(tile * 2 + rt) * 4096;
                #pragma unroll
                for (int nt = 0; nt < 4; ++nt) {
                    f32x4 v = acc[rt][nt];
                    racc[nt * 4 + 0] += fabsf(v[0]);
                    racc[nt * 4 + 1] += fabsf(v[1]);
                    racc[nt * 4 + 2] += fabsf(v[2]);
                    racc[nt * 4 + 3] += fabsf(v[3]);
                    unsigned lo = (unsigned)f2bf(v[0]) | ((unsigned)f2bf(v[1]) << 16);
                    unsigned hi = (unsigned)f2bf(v[2]) | ((unsigned)f2bf(v[3]) << 16);
                    const int NT  = wave * 4 + nt;
                    const int kcs = NT >> 1;
                    const int qq  = (NT & 1) * 2 + (q >> 1);
                    const size_t off16 = rowbase
                        + (size_t)(((kcs * 4 + qq) << 7) + m * 8 + (q & 1) * 4);
                    *(u64*)&errB[off16] = ((u64)hi << 32) | lo;
                }
            }
            // vmcnt(32): newest 32 = stores_j(8)+stage_j(4)+stores_{j-1}(8)
            // +stage_{j-1}(4)+stores_{j-2}(8); drains exactly stage_{j-3}+older
            // — the buffer consumed NEXT iter. 2 iters of stage stay in flight.
            asm volatile("s_waitcnt vmcnt(32)" ::: "memory");
            __builtin_amdgcn_s_barrier();
            cur = (cur + 1) & 3;
        }

        // rad: reduce over 16 m-lanes, one atomic per n from m==0 lanes
        #pragma unroll
        for (int i = 0; i < 16; ++i) {
            float v = racc[i];
            v += __shfl_xor(v, 1);
            v += __shfl_xor(v, 2);
            v += __shfl_xor(v, 4);
            v += __shfl_xor(v, 8);
            if (m == 0) {
                int nt = i >> 2, vv = i & 3;
                atomicAdd(&rad_new[b * H + wave * 64 + nt * 16 + q * 4 + vv], v);
            }
        }
    }

    // ---- epilogue (all blocks): diag rows for RT = diagRTbase + bx ----
    const int diagRTbase = (E_old - H) >> 4;
    const float2* wp = (const float2*)WhhP;
    u16* dbase = errB + (size_t)(diagRTbase + bx) * 4096;
    #pragma unroll
    for (int iter = 0; iter < 8; ++iter) {
        int p = iter * 256 + tid;            // p < 2048 (one row-tile)
        int mm = (p >> 2) & 15;
        float dv = de_s[bx * 16 + mm];
        float2 w = wp[bx * 2048 + p];
        *(unsigned*)&dbase[2 * p] =
            (unsigned)f2bf(dv * w.x) | ((unsigned)f2bf(dv * w.y) << 16);
    }
    // diag-rad slice: column GEMV over this block's 16 rows
    float s = 0.f;
    #pragma unroll
    for (int ii = 0; ii < 16; ++ii) {
        int i = bx * 16 + ii;
        s += fabsf(de_s[i]) * fabsf(Whh[(size_t)i * H + tid]);
    }
    atomicAdd(&rad_new[b * H + tid], s);

    if (bx == GNB - 1) {                     // head GEMV (fewest-tiles block)
        if (tid < N_IN) {
            float x = Xt[b * N_IN + tid], e = eps[b];
            float l2 = fmaxf(x - e, CLAMP_MIN), u2 = fminf(x + e, CLAMP_MAX);
            hx_s[tid] = 0.5f * (l2 + u2);
        }
        __syncthreads();
        float acc = bih[tid] + bhh[tid];
        #pragma unroll 8
        for (int i = 0; i < N_IN; ++i) acc += hx_s[i] * Wih[i * H + tid];
        #pragma unroll 8
        for (int j = 0; j < H; ++j) acc += hh_s[j] * Whh[j * H + tid];
        hp_new[b * H + tid] = acc;
    }
}

// ---------------------------------------------------------------------------
__global__ __launch_bounds__(256) void tanh_final_k(
    const float* __restrict__ hp, const float* __restrict__ rad,
    float* __restrict__ lam, float* __restrict__ de, float* __restrict__ head_h)
{
    const int b = blockIdx.x, h = threadIdx.x;
    float hd = hp[b * H + h], r = rad[b * H + h];
    float l = hd - r, u = hd + r;
    float tl = tanhf(l), tu = tanhf(u);
    float la = fminf(1.f - tl * tl, 1.f - tu * tu);
    float mu = 0.5f * (tu + tl - la * (u + l));
    float dd = 0.5f * (tu - tl - la * (u - l));
    lam[b * H + h] = la;
    de[b * H + h]  = dd;
    head_h[b * H + h] = la * hd + mu;
}

// ---------------------------------------------------------------------------
// pack WoT frag-packed (layout B), lam folded. grid Bc x 256.
// ---------------------------------------------------------------------------
__global__ __launch_bounds__(256) void packWoT_k(
    const float* __restrict__ WoT32, const float* __restrict__ lam,
    u16* __restrict__ WoTp)
{
    const int b = blockIdx.x, tid = threadIdx.x;
    __shared__ float lam_s[H];
    lam_s[tid] = lam[b * H + tid];
    __syncthreads();
    u16* dst = WoTp + (size_t)b * N_OUT * H;
    #pragma unroll 4
    for (int iter = 0; iter < 32; ++iter) {
        int p = iter * 256 + tid;
        int vb = (p & 1) * 2, hh = (p >> 1) & 1, m = (p >> 2) & 15, qq = (p >> 6) & 3;
        int KC = (p >> 8) & 7, RT = p >> 11;   // RT < 4
        int n = RT * 16 + m, k = KC * 32 + qq * 8 + hh * 4 + vb;
        *(unsigned*)&dst[2 * p] =
              (unsigned)f2bf(lam_s[k]     * WoT32[(size_t)n * H + k])
            | ((unsigned)f2bf(lam_s[k + 1] * WoT32[(size_t)n * H + k + 1]) << 16);
    }
}

// ---------------------------------------------------------------------------
__global__ void head_out_k(
    const float* __restrict__ head_h, const float* __restrict__ de,
    const float* __restrict__ Wo, const float* __restrict__ bo,
    float* __restrict__ head_out, float* __restrict__ rad_out)
{
    const int b = blockIdx.x, o = threadIdx.x;
    float acc = bo[o], accR = 0.f;
    #pragma unroll 4
    for (int j = 0; j < H; ++j) {
        float w = Wo[j * N_OUT + o];
        acc  += head_h[b * H + j] * w;
        accR += fabsf(de[b * H + j] * w);
    }
    head_out[b * N_OUT + o] = acc;
    rad_out[b * N_OUT + o]  = accR;
}

// ---------------------------------------------------------------------------
// final radius: rad_out += sum_rows |err @ WoTp^T| over all ESTRIDE rows.
// ---------------------------------------------------------------------------
__global__ __launch_bounds__(256) void gemm_out_k(
    const u16* __restrict__ err, const u16* __restrict__ WoTp,
    float* __restrict__ rad_out)
{
    __shared__ float rad_s[N_OUT];
    const int b = blockIdx.y, row0 = blockIdx.x * 256, tid = threadIdx.x;
    const int wave = tid >> 6, lane = tid & 63;
    const int m = lane & 15, q = lane >> 4;
    const u16* errB = err + (size_t)b * ESTRIDE * H;
    const u16* Wb   = WoTp + (size_t)b * N_OUT * H;

    if (tid < N_OUT) rad_s[tid] = 0.f;
    __syncthreads();

    f32x4 acc[4][4];
    #pragma unroll
    for (int i = 0; i < 4; ++i)
        #pragma unroll
        for (int c = 0; c < 4; ++c) acc[i][c] = (f32x4){0.f, 0.f, 0.f, 0.f};

    const int tile0 = (row0 >> 4) + wave * 4;
    #pragma unroll
    for (int kc = 0; kc < 8; ++kc) {
        bf16x8 af[4], bw[4];
        #pragma unroll
        for (int rt = 0; rt < 4; ++rt)
            af[rt] = *(const bf16x8*)
                &errB[(size_t)(((((tile0 + rt) * 8 + kc) * 4 + q) << 7) + m * 8)];
        #pragma unroll
        for (int nt = 0; nt < 4; ++nt)
            bw[nt] = *(const bf16x8*)
                &Wb[(size_t)((((nt * 8 + kc) * 4 + q) << 7) + m * 8)];
        #pragma unroll
        for (int nt = 0; nt < 4; ++nt)
            #pragma unroll
            for (int rt = 0; rt < 4; ++rt)
                acc[rt][nt] = __builtin_amdgcn_mfma_f32_16x16x32_bf16(
                    af[rt], bw[nt], acc[rt][nt], 0, 0, 0);
    }
    #pragma unroll
    for (int nt = 0; nt < 4; ++nt) {
        float s = 0.f;
        #pragma unroll
        for (int rt = 0; rt < 4; ++rt)
            #pragma unroll
            for (int r = 0; r < 4; ++r) s += fabsf(acc[rt][nt][r]);
        atomicAdd(&rad_s[nt * 16 + m], s);
    }
    __syncthreads();
    if (tid < N_OUT) atomicAdd(&rad_out[b * N_OUT + tid], rad_s[tid]);
}

// ---------------------------------------------------------------------------
__global__ void combine_k(const float* __restrict__ head_out,
                          const float* __restrict__ rad_out,
                          float* __restrict__ out)
{
    int i = blockIdx.x * 256 + threadIdx.x;
    if (i < BSZ * N_OUT) {
        float h = head_out[i], r = rad_out[i];
        out[i]               = h - r;
        out[BSZ * N_OUT + i] = h + r;
    }
}

// ---------------------------------------------------------------------------
extern "C" void kernel_launch(void* const* d_in, const int* in_sizes, int n_in,
                              void* d_out, int out_size, void* d_ws, size_t ws_size,
                              hipStream_t stream)
{
    const float* X    = (const float*)d_in[0];
    const float* eps  = (const float*)d_in[1];
    const float* Wih  = (const float*)d_in[2];
    const float* Whh  = (const float*)d_in[3];
    const float* bih  = (const float*)d_in[4];
    const float* bhh  = (const float*)d_in[5];
    const float* Wo   = (const float*)d_in[6];
    const float* bo   = (const float*)d_in[7];
    float* out = (float*)d_out;

    const size_t per_sample = (size_t)ESTRIDE * H * 2 + (size_t)N_OUT * H * 2;
    const size_t shared_b = (size_t)H * H * 4       // WhhT32
                          + (size_t)N_OUT * H * 4   // WoT32
                          + (size_t)N_IN * H * 4    // WihP
                          + (size_t)H * H * 4       // WhhP
                          + (size_t)H * H * 2       // WhhTp
                          + (size_t)2 * BSZ * H * 4                      // hp[2]
                          + (size_t)T_STEPS * BSZ * H * 4                // radT
                          + (size_t)3 * BSZ * H * 4                      // lam/de/head_h
                          + (size_t)2 * BSZ * N_OUT * 4 + 256;
    int Bc = BSZ;
    while (Bc > 1 && (size_t)Bc * per_sample + shared_b > ws_size) Bc >>= 1;

    char* p = (char*)d_ws;
    u16* errP      = (u16*)p;   p += (size_t)Bc * ESTRIDE * H * 2;
    u16* WoTp      = (u16*)p;   p += (size_t)Bc * N_OUT * H * 2;
    u16* WhhTp     = (u16*)p;   p += (size_t)H * H * 2;
    float* WhhT32  = (float*)p; p += (size_t)H * H * 4;
    float* WoT32   = (float*)p; p += (size_t)N_OUT * H * 4;
    float* WihP    = (float*)p; p += (size_t)N_IN * H * 4;
    float* WhhP    = (float*)p; p += (size_t)H * H * 4;
    float* hp      = (float*)p; p += (size_t)2 * BSZ * H * 4;
    float* radT    = (float*)p; p += (size_t)T_STEPS * BSZ * H * 4;
    float* lam     = (float*)p; p += (size_t)BSZ * H * 4;
    float* de      = (float*)p; p += (size_t)BSZ * H * 4;
    float* head_h  = (float*)p; p += (size_t)BSZ * H * 4;
    float* head_out= (float*)p; p += (size_t)BSZ * N_OUT * 4;
    float* rad_out = (float*)p;

    transpose_k<<<dim3(H / 32, H / 32), 256, 0, stream>>>(Whh, WhhT32, H, H);
    transpose_k<<<dim3(N_OUT / 32, H / 32), 256, 0, stream>>>(Wo, WoT32, H, N_OUT);
    packPairs_k<<<(N_IN * 128) / 256, 256, 0, stream>>>(Wih, WihP);
    packPairs_k<<<(H * 128) / 256, 256, 0, stream>>>(Whh, WhhP);
    packWT_k<<<128, 256, 0, stream>>>(WhhT32, WhhTp);

    for (int b0 = 0; b0 < BSZ; b0 += Bc) {
        prefresh_k<<<dim3(T_STEPS, Bc), 256, 0, stream>>>(
            X + (size_t)b0 * N_IN, eps + b0, Wih, WihP, bih, bhh, errP,
            radT + (size_t)b0 * H, hp + (size_t)b0 * H);
        for (int t = 1; t < T_STEPS; ++t) {
            int E_old = t * (N_IN + H);
            const float* hp_prev = hp + (size_t)((t - 1) & 1) * BSZ * H + (size_t)b0 * H;
            float*       hp_new  = hp + (size_t)(t & 1) * BSZ * H + (size_t)b0 * H;
            const float* rad_prev = radT + (size_t)(t - 1) * BSZ * H + (size_t)b0 * H;
            float*       rad_new  = radT + (size_t)t * BSZ * H + (size_t)b0 * H;
            step_k<<<dim3(GNB, Bc), 256, 0, stream>>>(
                X + (size_t)(t * BSZ + b0) * N_IN, eps + b0, Wih, Whh,
                WhhP, WhhTp, bih, bhh, hp_prev, rad_prev, hp_new, rad_new,
                errP, E_old);
        }
        const float* hp_last = hp + (size_t)((T_STEPS - 1) & 1) * BSZ * H + (size_t)b0 * H;
        const float* rad_last = radT + (size_t)(T_STEPS - 1) * BSZ * H + (size_t)b0 * H;
        tanh_final_k<<<Bc, 256, 0, stream>>>(
            hp_last, rad_last, lam + (size_t)b0 * H, de + (size_t)b0 * H,
            head_h + (size_t)b0 * H);
        packWoT_k<<<Bc, 256, 0, stream>>>(WoT32, lam + (size_t)b0 * H, WoTp);
        head_out_k<<<Bc, 64, 0, stream>>>(
            head_h + (size_t)b0 * H, de + (size_t)b0 * H, Wo, bo,
            head_out + (size_t)b0 * N_OUT, rad_out + (size_t)b0 * N_OUT);
        gemm_out_k<<<dim3(ESTRIDE / 256, Bc), 256, 0, stream>>>(
            errP, WoTp, rad_out + (size_t)b0 * N_OUT);
    }

    combine_k<<<(BSZ * N_OUT + 255) / 256, 256, 0, stream>>>(head_out, rad_out, out);
}